// Round 7
// baseline (149.512 us; speedup 1.0000x reference)
//
#include <hip/hip_runtime.h>
#include <hip/hip_bf16.h>

#define LN_EPS 1e-5f

typedef __attribute__((ext_vector_type(8))) short bf16x8_t;
typedef __attribute__((ext_vector_type(4))) short bf16x4_t;
typedef __attribute__((ext_vector_type(4))) float f32x4_t;
typedef __attribute__((ext_vector_type(4))) unsigned short u16x4_t;

#define MFMA32(a, b, c) __builtin_amdgcn_mfma_f32_16x16x32_bf16(a, b, c, 0, 0, 0)
#define MFMA16(a, b, c) __builtin_amdgcn_mfma_f32_16x16x16bf16_1k(a, b, c, 0, 0, 0)

__device__ inline unsigned short f2bf(float f) {
    union { float f; unsigned int u; } v; v.f = f;
    unsigned int r = v.u + 0x7fffu + ((v.u >> 16) & 1u);
    return (unsigned short)(r >> 16);
}

__device__ inline u16x4_t pk4(float a, float b, float c, float d) {
    union { u16x4_t v; __hip_bfloat162 h[2]; } u;
    u.h[0] = __float22bfloat162_rn(float2{a, b});
    u.h[1] = __float22bfloat162_rn(float2{c, d});
    return u.v;
}
__device__ inline bf16x4_t pk4b(float a, float b, float c, float d) {
    union { bf16x4_t v; __hip_bfloat162 h[2]; } u;
    u.h[0] = __float22bfloat162_rn(float2{a, b});
    u.h[1] = __float22bfloat162_rn(float2{c, d});
    return u.v;
}
__device__ inline bf16x8_t pk8(float4 a, float4 b) {
    union { bf16x8_t v; __hip_bfloat162 h[4]; } u;
    u.h[0] = __float22bfloat162_rn(float2{a.x, a.y});
    u.h[1] = __float22bfloat162_rn(float2{a.z, a.w});
    u.h[2] = __float22bfloat162_rn(float2{b.x, b.y});
    u.h[3] = __float22bfloat162_rn(float2{b.z, b.w});
    return u.v;
}

// Fragment-layout index for [ROWS][KD] stored as MFMA fragments:
// tile (row>>4, k>>5) = 512 contiguous u16; lane=((k>>3)&3)*16+(row&15), j=k&7.
__device__ inline size_t fragidx(int row, int k, int KC) {
    return ((size_t)((row >> 4) * KC + (k >> 5))) * 512 +
           (((k >> 3) & 3) * 16 + (row & 15)) * 8 + (k & 7);
}

// ---------------------------------------------------------------------------
__global__ void k_prep_w(const float* __restrict__ qW, const float* __restrict__ kvW,
                         const float* __restrict__ projW, const float* __restrict__ srW,
                         unsigned short* __restrict__ qWs, unsigned short* __restrict__ kvWs,
                         unsigned short* __restrict__ projWs, unsigned short* __restrict__ srWs) {
    int i = blockIdx.x * 256 + threadIdx.x;
    if (i < 16384) {
        int n = i & 127, k = i >> 7;
        qWs[fragidx(n, k, 4)] = f2bf(qW[k * 128 + n]);
    } else if (i < 49152) {
        int j = i - 16384; int n = j & 255, k = j >> 8;
        kvWs[fragidx(n, k, 4)] = f2bf(kvW[k * 256 + n]);
    } else if (i < 65536) {
        int j = i - 49152; int n = j & 127, k = j >> 7;
        projWs[fragidx(n, k, 4)] = f2bf(projW[k * 128 + n]);
    } else {
        int j = i - 65536; int n = j >> 9, rem = j & 511, q = rem >> 7, c = rem & 127;
        srWs[fragidx(n, q * 128 + c, 16)] = f2bf(srW[n * 512 + c * 4 + q]);
    }
}

// ---------------------------------------------------------------------------
// Fused SR-conv + bias + LayerNorm + kv-projection. Conv patches are loaded
// DIRECTLY from x (fp32) and converted in-register (prep_x eliminated).
// Grid 512 (16 positions/block), block 256 = 4 waves.
// K -> ksw A-frags; V -> vls K16-B-operand layout.
__global__ __launch_bounds__(256)
void k_convkv(const float* __restrict__ x, const unsigned short* __restrict__ srWs,
              const float* __restrict__ srb, const float* __restrict__ lnW,
              const float* __restrict__ lnB, const unsigned short* __restrict__ kvWs,
              const float* __restrict__ kvb, unsigned short* __restrict__ ksw,
              unsigned short* __restrict__ vls) {
    const int t = threadIdx.x, w = t >> 6, lane = t & 63;
    const int col = lane & 15, quad = lane >> 4;
    const int RT = blockIdx.x;                 // row-tile 0..511

    __shared__ unsigned short xs[4 * 512];
    __shared__ float lnred[4][16][2];

    // x-row bases for this lane's conv position, per kernel tap q
    const int pos = RT * 16 + col;
    const int pb = pos >> 11, phf = (pos >> 10) & 1;
    const int poy = (pos >> 5) & 31, pox = pos & 31;
    int rowbase[4];
    #pragma unroll
    for (int q = 0; q < 4; q++) {
        int ky = q >> 1, kx = q & 1;
        int n = phf * 4096 + (2 * poy + ky) * 64 + 2 * pox + kx;
        rowbase[q] = (pb * 8192 + n) * 128;
    }

    // conv (transposed): wave w computes feature-tiles {2w, 2w+1}
    f32x4_t acc[2] = {};
    {
        const unsigned short* wp = srWs + lane * 8;
        #pragma unroll
        for (int kc = 0; kc < 16; kc++) {
            const float* xr = x + rowbase[kc >> 2] + (kc & 3) * 32 + quad * 8;
            float4 xa = *(const float4*)(xr);
            float4 xb2 = *(const float4*)(xr + 4);
            bf16x8_t xb = pk8(xa, xb2);
            #pragma unroll
            for (int jj = 0; jj < 2; jj++) {
                bf16x8_t wf = *(const bf16x8_t*)(wp + (size_t)((w * 2 + jj) * 16 + kc) * 512);
                acc[jj] = MFMA32(wf, xb, acc[jj]);
            }
        }
    }
    // + bias, moments
    float s = 0.f, ss = 0.f;
    #pragma unroll
    for (int jj = 0; jj < 2; jj++) {
        float4 bs = *(const float4*)(srb + (w * 2 + jj) * 16 + quad * 4);
        acc[jj][0] += bs.x; acc[jj][1] += bs.y; acc[jj][2] += bs.z; acc[jj][3] += bs.w;
        #pragma unroll
        for (int r = 0; r < 4; r++) { float v = acc[jj][r]; s += v; ss += v * v; }
    }
    s += __shfl_xor(s, 16, 64);  s += __shfl_xor(s, 32, 64);
    ss += __shfl_xor(ss, 16, 64); ss += __shfl_xor(ss, 32, 64);
    if (lane < 16) { lnred[w][lane][0] = s; lnred[w][lane][1] = ss; }
    __syncthreads();
    float stot = 0.f, sstot = 0.f;
    #pragma unroll
    for (int ww = 0; ww < 4; ww++) { stot += lnred[ww][col][0]; sstot += lnred[ww][col][1]; }
    float mean = stot * (1.0f / 128.0f);
    float var = sstot * (1.0f / 128.0f) - mean * mean;
    float rs = rsqrtf(var + LN_EPS);
    #pragma unroll
    for (int jj = 0; jj < 2; jj++) {
        int f0 = (w * 2 + jj) * 16 + quad * 4;
        float4 g = *(const float4*)(lnW + f0);
        float4 be = *(const float4*)(lnB + f0);
        u16x4_t o = pk4((acc[jj][0] - mean) * rs * g.x + be.x,
                        (acc[jj][1] - mean) * rs * g.y + be.y,
                        (acc[jj][2] - mean) * rs * g.z + be.z,
                        (acc[jj][3] - mean) * rs * g.w + be.w);
        *(u16x4_t*)(xs + ((size_t)(f0 >> 5)) * 512 +
                    (((f0 >> 3) & 3) * 16 + col) * 8 + (f0 & 7)) = o;
    }
    __syncthreads();
    bf16x8_t xf[4];
    #pragma unroll
    for (int kc = 0; kc < 4; kc++)
        xf[kc] = *(const bf16x8_t*)(xs + (size_t)kc * 512 + lane * 8);
    const int p0 = RT * 16;
    const int bb = p0 >> 11;
    // K (transposed): feature-tiles {2w, 2w+1}
    #pragma unroll
    for (int jj = 0; jj < 2; jj++) {
        const int nt = w * 2 + jj;
        f32x4_t aK = {};
        #pragma unroll
        for (int kc = 0; kc < 4; kc++) {
            bf16x8_t wf = *(const bf16x8_t*)(kvWs + (size_t)(nt * 4 + kc) * 512 + lane * 8);
            aK = MFMA32(wf, xf[kc], aK);
        }
        float4 bs = *(const float4*)(kvb + nt * 16 + quad * 4);
        int m = (p0 + col) & 2047;
        int bh = bb * 2 + (nt >> 2);
        int d0 = (nt & 3) * 16 + quad * 4;
        u16x4_t o = pk4(aK[0] + bs.x, aK[1] + bs.y, aK[2] + bs.z, aK[3] + bs.w);
        *(u16x4_t*)(ksw + ((size_t)(bh * 128 + (m >> 4)) * 2 + (d0 >> 5)) * 512 +
                    (((d0 >> 3) & 3) * 16 + (m & 15)) * 8 + (d0 & 7)) = o;
    }
    // V (normal): feature-tiles {2w, 2w+1} of V's 8 -> vls K16-B layout
    #pragma unroll
    for (int jj = 0; jj < 2; jj++) {
        const int nt = w * 2 + jj;
        f32x4_t aV = {};
        #pragma unroll
        for (int kc = 0; kc < 4; kc++) {
            bf16x8_t wf = *(const bf16x8_t*)(kvWs + (size_t)((8 + nt) * 4 + kc) * 512 + lane * 8);
            aV = MFMA32(xf[kc], wf, aV);
        }
        int fv = nt * 16 + col;
        int h = fv >> 6, dd = fv & 63;
        float bv = kvb[128 + fv];
        int m0 = (p0 + quad * 4) & 2047;
        int bh = bb * 2 + h;
        int kt = m0 >> 6, nb = (m0 >> 4) & 3;
        u16x4_t o = pk4(aV[0] + bv, aV[1] + bv, aV[2] + bv, aV[3] + bv);
        *(u16x4_t*)(vls + (((size_t)(bh * 32 + kt) * 4 + (dd >> 4)) * 2 + (nb >> 1)) * 512 +
                    (quad * 16 + (dd & 15)) * 8 + (nb & 1) * 4) = o;
    }
}

// ---------------------------------------------------------------------------
// Fused q-proj + KEY-SPLIT attention + out-proj.
// Block 256 = 4 waves (h = w&1, ks = w>>1); 32 queries/block, both heads,
// keys split in half across ks. Softmax has no max-tracking, so the split
// combine is a pure ADD of O and l. Grid (128,2,4) = 1024 blocks -> 4 w/SIMD.
__global__ __launch_bounds__(256)
void k_attn_f3(const float* __restrict__ x, const unsigned short* __restrict__ qWs,
               const float* __restrict__ qb, const unsigned short* __restrict__ ksw,
               const unsigned short* __restrict__ vls, const unsigned short* __restrict__ projWs,
               const float* __restrict__ projb, float* __restrict__ out) {
    const int blkx = blockIdx.x, mod = blockIdx.y, b = blockIdx.z;
    const int t = threadIdx.x, w = t >> 6, lane = t & 63;
    const int col = lane & 15, quad = lane >> 4;
    const int h = w & 1, ks = w >> 1;
    const int bh = b * 2 + h;
    const int qbase = mod * 4096 + blkx * 32;   // within batch b

    __shared__ float Ocomb[2 * 32 * 64];        // 16 KB: ks=1 halves
    __shared__ float lcomb[64];
    __shared__ unsigned short rows[32 * 136];   // 8.5 KB O rows (bf16)
    __shared__ unsigned short qfr[2 * 4 * 512]; // 8 KB Q frags

    // ---- q-proj: wave (h,ks) computes q-tile qt=ks of head h (no redundancy)
    {
        const int qt = ks;
        const float* xrow = x + ((size_t)b * 8192 + qbase + qt * 16 + col) * 128;
        const float sc = 0.125f * 1.44269504089f;
        f32x4_t acc[4] = {};
        #pragma unroll
        for (int kc = 0; kc < 4; kc++) {
            float4 xa = *(const float4*)(xrow + kc * 32 + quad * 8);
            float4 xb2 = *(const float4*)(xrow + kc * 32 + quad * 8 + 4);
            bf16x8_t xf = pk8(xa, xb2);
            #pragma unroll
            for (int j = 0; j < 4; j++) {
                bf16x8_t wf = *(const bf16x8_t*)(qWs + (size_t)((h * 4 + j) * 4 + kc) * 512 + lane * 8);
                acc[j] = MFMA32(wf, xf, acc[j]);
            }
        }
        #pragma unroll
        for (int j = 0; j < 4; j++) {
            float4 bs = *(const float4*)(qb + h * 64 + j * 16 + quad * 4);
            u16x4_t o = pk4((acc[j][0] + bs.x) * sc, (acc[j][1] + bs.y) * sc,
                            (acc[j][2] + bs.z) * sc, (acc[j][3] + bs.w) * sc);
            *(u16x4_t*)(qfr + (size_t)h * 2048 + ((size_t)(qt * 2 + (j >> 1))) * 512 +
                        (((j & 1) * 2 + (quad >> 1)) * 16 + col) * 8 + (quad & 1) * 4) = o;
        }
    }
    __syncthreads();
    bf16x8_t qf[2][2];
    #pragma unroll
    for (int qt = 0; qt < 2; qt++)
        #pragma unroll
        for (int kc = 0; kc < 2; kc++)
            qf[qt][kc] = *(const bf16x8_t*)(qfr + (size_t)h * 2048 +
                                            (size_t)(qt * 2 + kc) * 512 + lane * 8);

    const unsigned short* kp0 =
        ksw + ((size_t)(bh * 128 + (1 - mod) * 64) * 2) * 512 + lane * 8;
    const unsigned short* vp0 =
        vls + ((size_t)(bh * 32 + (1 - mod) * 16) * 8) * 512 + lane * 8;
    const bf16x4_t ones4 = { 0x3F80, 0x3F80, 0x3F80, 0x3F80 };

    f32x4_t O[2][4] = {};
    f32x4_t accl[2] = {};

    for (int kt = ks * 8; kt < ks * 8 + 8; kt++) {
        bf16x8_t kf[8];
        #pragma unroll
        for (int i = 0; i < 8; i++)
            kf[i] = *(const bf16x8_t*)(kp0 + (size_t)(kt * 8 + i) * 512);
        union { bf16x8_t v8; bf16x4_t v4[2]; } vf[8];
        #pragma unroll
        for (int i = 0; i < 8; i++)
            vf[i].v8 = *(const bf16x8_t*)(vp0 + (size_t)(kt * 8 + i) * 512);
        // S^T = K·Q^T
        f32x4_t ST[2][4];
        #pragma unroll
        for (int qt = 0; qt < 2; qt++)
            #pragma unroll
            for (int nb = 0; nb < 4; nb++) {
                f32x4_t sA = {};
                sA = MFMA32(kf[nb * 2 + 0], qf[qt][0], sA);
                sA = MFMA32(kf[nb * 2 + 1], qf[qt][1], sA);
                ST[qt][nb] = sA;
            }
        // exp2 -> P directly in K16 A-operand registers
        bf16x4_t pa[2][4];
        #pragma unroll
        for (int qt = 0; qt < 2; qt++)
            #pragma unroll
            for (int nb = 0; nb < 4; nb++)
                pa[qt][nb] = pk4b(exp2f(ST[qt][nb][0]), exp2f(ST[qt][nb][1]),
                                  exp2f(ST[qt][nb][2]), exp2f(ST[qt][nb][3]));
        #pragma unroll
        for (int qt = 0; qt < 2; qt++) {
            #pragma unroll
            for (int nb = 0; nb < 4; nb++) {
                accl[qt] = MFMA16(pa[qt][nb], ones4, accl[qt]);
                #pragma unroll
                for (int dt = 0; dt < 4; dt++)
                    O[qt][dt] = MFMA16(pa[qt][nb], vf[dt * 2 + (nb >> 1)].v4[nb & 1], O[qt][dt]);
            }
        }
    }

    // ---- key-split combine: ks=1 deposits raw O and l; ks=0 adds
    if (ks == 1) {
        #pragma unroll
        for (int qt = 0; qt < 2; qt++)
            #pragma unroll
            for (int r = 0; r < 4; r++) {
                int qrow = qt * 16 + quad * 4 + r;
                #pragma unroll
                for (int dt = 0; dt < 4; dt++)
                    Ocomb[(h * 32 + qrow) * 64 + dt * 16 + col] = O[qt][dt][r];
                if (col == 0) lcomb[h * 32 + qrow] = accl[qt][r];
            }
    }
    __syncthreads();
    if (ks == 0) {
        #pragma unroll
        for (int qt = 0; qt < 2; qt++)
            #pragma unroll
            for (int r = 0; r < 4; r++) {
                int qrow = qt * 16 + quad * 4 + r;
                float lt = accl[qt][r] + lcomb[h * 32 + qrow];
                float rl = 1.0f / lt;
                #pragma unroll
                for (int dt = 0; dt < 4; dt++) {
                    float ov = O[qt][dt][r] + Ocomb[(h * 32 + qrow) * 64 + dt * 16 + col];
                    rows[qrow * 136 + h * 64 + dt * 16 + col] = f2bf(ov * rl);
                }
            }
    }
    __syncthreads();
    // ---- out-proj: waves 0,1 (ks=0) -> q-tile h
    if (ks == 0) {
        const int qt2 = h;
        bf16x8_t ob[4];
        #pragma unroll
        for (int kc = 0; kc < 4; kc++)
            ob[kc] = *(const bf16x8_t*)(rows + (size_t)(qt2 * 16 + col) * 136 + kc * 32 + quad * 8);
        f32x4_t acc[8];
        #pragma unroll
        for (int j = 0; j < 8; j++) acc[j] = f32x4_t{};
        #pragma unroll
        for (int kc = 0; kc < 4; kc++)
            #pragma unroll
            for (int j = 0; j < 8; j++) {
                bf16x8_t wf = *(const bf16x8_t*)(projWs + (size_t)(j * 4 + kc) * 512 + lane * 8);
                acc[j] = MFMA32(wf, ob[kc], acc[j]);
            }
        const int n = b * 8192 + qbase + qt2 * 16 + col;
        #pragma unroll
        for (int j = 0; j < 8; j++) {
            int f0 = j * 16 + quad * 4;
            float4 bs = *(const float4*)(projb + f0);
            float4 o = { acc[j][0] + bs.x, acc[j][1] + bs.y,
                         acc[j][2] + bs.z, acc[j][3] + bs.w };
            *(float4*)(out + (size_t)n * 128 + f0) = o;
        }
    }
}

// ---------------------------------------------------------------------------
extern "C" void kernel_launch(void* const* d_in, const int* in_sizes, int n_in,
                              void* d_out, int out_size, void* d_ws, size_t ws_size,
                              hipStream_t stream) {
    const float* x     = (const float*)d_in[0];
    const float* qW    = (const float*)d_in[1];
    const float* qb    = (const float*)d_in[2];
    const float* kvW   = (const float*)d_in[3];
    const float* kvb   = (const float*)d_in[4];
    const float* projW = (const float*)d_in[5];
    const float* projb = (const float*)d_in[6];
    const float* srW   = (const float*)d_in[7];
    const float* srb   = (const float*)d_in[8];
    const float* lnW   = (const float*)d_in[9];
    const float* lnB   = (const float*)d_in[10];

    char* ws = (char*)d_ws;
    unsigned short* qWs    = (unsigned short*)(ws + 0);         // 32 KB
    unsigned short* kvWs   = (unsigned short*)(ws + 32768);     // 64 KB
    unsigned short* projWs = (unsigned short*)(ws + 98304);     // 32 KB
    unsigned short* srWs   = (unsigned short*)(ws + 131072);    // 128 KB
    unsigned short* ksw    = (unsigned short*)(ws + 262144);    // 2 MB
    unsigned short* vls    = (unsigned short*)(ws + 2359296);   // 2 MB

    k_prep_w<<<dim3(512), dim3(256), 0, stream>>>(qW, kvW, projW, srW,
                                                  qWs, kvWs, projWs, srWs);
    k_convkv<<<dim3(512), dim3(256), 0, stream>>>(x, srWs, srb, lnW, lnB,
                                                  kvWs, kvb, ksw, vls);
    k_attn_f3<<<dim3(128, 2, 4), dim3(256), 0, stream>>>(x, qWs, qb, ksw, vls,
                                                         projWs, projb, (float*)d_out);
}

// Round 8
// 147.802 us; speedup vs baseline: 1.0116x; 1.0116x over previous
//
#include <hip/hip_runtime.h>
#include <hip/hip_bf16.h>

#define LN_EPS 1e-5f

typedef __attribute__((ext_vector_type(8))) short bf16x8_t;
typedef __attribute__((ext_vector_type(4))) short bf16x4_t;
typedef __attribute__((ext_vector_type(4))) float f32x4_t;
typedef __attribute__((ext_vector_type(4))) unsigned short u16x4_t;

#define MFMA32(a, b, c) __builtin_amdgcn_mfma_f32_16x16x32_bf16(a, b, c, 0, 0, 0)
#define MFMA16(a, b, c) __builtin_amdgcn_mfma_f32_16x16x16bf16_1k(a, b, c, 0, 0, 0)

__device__ inline unsigned short f2bf(float f) {
    union { float f; unsigned int u; } v; v.f = f;
    unsigned int r = v.u + 0x7fffu + ((v.u >> 16) & 1u);
    return (unsigned short)(r >> 16);
}

__device__ inline u16x4_t pk4(float a, float b, float c, float d) {
    union { u16x4_t v; __hip_bfloat162 h[2]; } u;
    u.h[0] = __float22bfloat162_rn(float2{a, b});
    u.h[1] = __float22bfloat162_rn(float2{c, d});
    return u.v;
}
__device__ inline bf16x4_t pk4b(float a, float b, float c, float d) {
    union { bf16x4_t v; __hip_bfloat162 h[2]; } u;
    u.h[0] = __float22bfloat162_rn(float2{a, b});
    u.h[1] = __float22bfloat162_rn(float2{c, d});
    return u.v;
}
__device__ inline bf16x8_t pk8(float4 a, float4 b) {
    union { bf16x8_t v; __hip_bfloat162 h[4]; } u;
    u.h[0] = __float22bfloat162_rn(float2{a.x, a.y});
    u.h[1] = __float22bfloat162_rn(float2{a.z, a.w});
    u.h[2] = __float22bfloat162_rn(float2{b.x, b.y});
    u.h[3] = __float22bfloat162_rn(float2{b.z, b.w});
    return u.v;
}

// Fragment-layout index for [ROWS][KD] stored as MFMA fragments:
// tile (row>>4, k>>5) = 512 contiguous u16; lane=((k>>3)&3)*16+(row&15), j=k&7.
__device__ inline size_t fragidx(int row, int k, int KC) {
    return ((size_t)((row >> 4) * KC + (k >> 5))) * 512 +
           (((k >> 3) & 3) * 16 + (row & 15)) * 8 + (k & 7);
}

// ---------------------------------------------------------------------------
__global__ void k_prep_w(const float* __restrict__ qW, const float* __restrict__ kvW,
                         const float* __restrict__ projW, const float* __restrict__ srW,
                         unsigned short* __restrict__ qWs, unsigned short* __restrict__ kvWs,
                         unsigned short* __restrict__ projWs, unsigned short* __restrict__ srWs) {
    int i = blockIdx.x * 256 + threadIdx.x;
    if (i < 16384) {
        int n = i & 127, k = i >> 7;
        qWs[fragidx(n, k, 4)] = f2bf(qW[k * 128 + n]);
    } else if (i < 49152) {
        int j = i - 16384; int n = j & 255, k = j >> 8;
        kvWs[fragidx(n, k, 4)] = f2bf(kvW[k * 256 + n]);
    } else if (i < 65536) {
        int j = i - 49152; int n = j & 127, k = j >> 7;
        projWs[fragidx(n, k, 4)] = f2bf(projW[k * 128 + n]);
    } else {
        int j = i - 65536; int n = j >> 9, rem = j & 511, q = rem >> 7, c = rem & 127;
        srWs[fragidx(n, q * 128 + c, 16)] = f2bf(srW[n * 512 + c * 4 + q]);
    }
}

// ---------------------------------------------------------------------------
// Fused SR-conv + bias + LayerNorm + kv-projection (unchanged from R7).
__global__ __launch_bounds__(256)
void k_convkv(const float* __restrict__ x, const unsigned short* __restrict__ srWs,
              const float* __restrict__ srb, const float* __restrict__ lnW,
              const float* __restrict__ lnB, const unsigned short* __restrict__ kvWs,
              const float* __restrict__ kvb, unsigned short* __restrict__ ksw,
              unsigned short* __restrict__ vls) {
    const int t = threadIdx.x, w = t >> 6, lane = t & 63;
    const int col = lane & 15, quad = lane >> 4;
    const int RT = blockIdx.x;

    __shared__ unsigned short xs[4 * 512];
    __shared__ float lnred[4][16][2];

    const int pos = RT * 16 + col;
    const int pb = pos >> 11, phf = (pos >> 10) & 1;
    const int poy = (pos >> 5) & 31, pox = pos & 31;
    int rowbase[4];
    #pragma unroll
    for (int q = 0; q < 4; q++) {
        int ky = q >> 1, kx = q & 1;
        int n = phf * 4096 + (2 * poy + ky) * 64 + 2 * pox + kx;
        rowbase[q] = (pb * 8192 + n) * 128;
    }

    f32x4_t acc[2] = {};
    {
        const unsigned short* wp = srWs + lane * 8;
        #pragma unroll
        for (int kc = 0; kc < 16; kc++) {
            const float* xr = x + rowbase[kc >> 2] + (kc & 3) * 32 + quad * 8;
            float4 xa = *(const float4*)(xr);
            float4 xb2 = *(const float4*)(xr + 4);
            bf16x8_t xb = pk8(xa, xb2);
            #pragma unroll
            for (int jj = 0; jj < 2; jj++) {
                bf16x8_t wf = *(const bf16x8_t*)(wp + (size_t)((w * 2 + jj) * 16 + kc) * 512);
                acc[jj] = MFMA32(wf, xb, acc[jj]);
            }
        }
    }
    float s = 0.f, ss = 0.f;
    #pragma unroll
    for (int jj = 0; jj < 2; jj++) {
        float4 bs = *(const float4*)(srb + (w * 2 + jj) * 16 + quad * 4);
        acc[jj][0] += bs.x; acc[jj][1] += bs.y; acc[jj][2] += bs.z; acc[jj][3] += bs.w;
        #pragma unroll
        for (int r = 0; r < 4; r++) { float v = acc[jj][r]; s += v; ss += v * v; }
    }
    s += __shfl_xor(s, 16, 64);  s += __shfl_xor(s, 32, 64);
    ss += __shfl_xor(ss, 16, 64); ss += __shfl_xor(ss, 32, 64);
    if (lane < 16) { lnred[w][lane][0] = s; lnred[w][lane][1] = ss; }
    __syncthreads();
    float stot = 0.f, sstot = 0.f;
    #pragma unroll
    for (int ww = 0; ww < 4; ww++) { stot += lnred[ww][col][0]; sstot += lnred[ww][col][1]; }
    float mean = stot * (1.0f / 128.0f);
    float var = sstot * (1.0f / 128.0f) - mean * mean;
    float rs = rsqrtf(var + LN_EPS);
    #pragma unroll
    for (int jj = 0; jj < 2; jj++) {
        int f0 = (w * 2 + jj) * 16 + quad * 4;
        float4 g = *(const float4*)(lnW + f0);
        float4 be = *(const float4*)(lnB + f0);
        u16x4_t o = pk4((acc[jj][0] - mean) * rs * g.x + be.x,
                        (acc[jj][1] - mean) * rs * g.y + be.y,
                        (acc[jj][2] - mean) * rs * g.z + be.z,
                        (acc[jj][3] - mean) * rs * g.w + be.w);
        *(u16x4_t*)(xs + ((size_t)(f0 >> 5)) * 512 +
                    (((f0 >> 3) & 3) * 16 + col) * 8 + (f0 & 7)) = o;
    }
    __syncthreads();
    bf16x8_t xf[4];
    #pragma unroll
    for (int kc = 0; kc < 4; kc++)
        xf[kc] = *(const bf16x8_t*)(xs + (size_t)kc * 512 + lane * 8);
    const int p0 = RT * 16;
    const int bb = p0 >> 11;
    #pragma unroll
    for (int jj = 0; jj < 2; jj++) {
        const int nt = w * 2 + jj;
        f32x4_t aK = {};
        #pragma unroll
        for (int kc = 0; kc < 4; kc++) {
            bf16x8_t wf = *(const bf16x8_t*)(kvWs + (size_t)(nt * 4 + kc) * 512 + lane * 8);
            aK = MFMA32(wf, xf[kc], aK);
        }
        float4 bs = *(const float4*)(kvb + nt * 16 + quad * 4);
        int m = (p0 + col) & 2047;
        int bh = bb * 2 + (nt >> 2);
        int d0 = (nt & 3) * 16 + quad * 4;
        u16x4_t o = pk4(aK[0] + bs.x, aK[1] + bs.y, aK[2] + bs.z, aK[3] + bs.w);
        *(u16x4_t*)(ksw + ((size_t)(bh * 128 + (m >> 4)) * 2 + (d0 >> 5)) * 512 +
                    (((d0 >> 3) & 3) * 16 + (m & 15)) * 8 + (d0 & 7)) = o;
    }
    #pragma unroll
    for (int jj = 0; jj < 2; jj++) {
        const int nt = w * 2 + jj;
        f32x4_t aV = {};
        #pragma unroll
        for (int kc = 0; kc < 4; kc++) {
            bf16x8_t wf = *(const bf16x8_t*)(kvWs + (size_t)((8 + nt) * 4 + kc) * 512 + lane * 8);
            aV = MFMA32(xf[kc], wf, aV);
        }
        int fv = nt * 16 + col;
        int h = fv >> 6, dd = fv & 63;
        float bv = kvb[128 + fv];
        int m0 = (p0 + quad * 4) & 2047;
        int bh = bb * 2 + h;
        int kt = m0 >> 6, nb = (m0 >> 4) & 3;
        u16x4_t o = pk4(aV[0] + bv, aV[1] + bv, aV[2] + bv, aV[3] + bv);
        *(u16x4_t*)(vls + (((size_t)(bh * 32 + kt) * 4 + (dd >> 4)) * 2 + (nb >> 1)) * 512 +
                    (quad * 16 + (dd & 15)) * 8 + (nb & 1) * 4) = o;
    }
}

// ---------------------------------------------------------------------------
// Fused q-proj + attention + out-proj with BLOCK-COOPERATIVE double-buffered
// LDS staging of K/V (m97 pattern, VGPR-pipelined): per kt the block stages
// 32 KB (K+V, both heads) once; 4 waves consume from LDS via ds_read_b128.
// Block 256 = 4 waves (qg = w&1, h = w>>1); grid (64, 2, 4) = 512 blocks.
__global__ __launch_bounds__(256)
void k_attn_f4(const float* __restrict__ x, const unsigned short* __restrict__ qWs,
               const float* __restrict__ qb, const unsigned short* __restrict__ ksw,
               const unsigned short* __restrict__ vls, const unsigned short* __restrict__ projWs,
               const float* __restrict__ projb, float* __restrict__ out) {
    const int blkx = blockIdx.x, mod = blockIdx.y, b = blockIdx.z;
    const int t = threadIdx.x, w = t >> 6, lane = t & 63;
    const int col = lane & 15, quad = lane >> 4;
    const int qg = w & 1, h = w >> 1;
    const int qbase = mod * 4096 + blkx * 64 + qg * 32;

    __shared__ char arena[65536];               // dbuf 2x32KB; aliased for Q/O
    unsigned short* sbuf = (unsigned short*)arena;

    // ---- q-proj: Q B-frags (scale*log2e folded), wave-local staging
    unsigned short* qarea = sbuf + w * 2048;
    const float sc = 0.125f * 1.44269504089f;
    #pragma unroll
    for (int qt = 0; qt < 2; qt++) {
        const float* xrow = x + ((size_t)b * 8192 + qbase + qt * 16 + col) * 128;
        f32x4_t acc[4] = {};
        #pragma unroll
        for (int kc = 0; kc < 4; kc++) {
            float4 xa = *(const float4*)(xrow + kc * 32 + quad * 8);
            float4 xb2 = *(const float4*)(xrow + kc * 32 + quad * 8 + 4);
            bf16x8_t xf = pk8(xa, xb2);
            #pragma unroll
            for (int j = 0; j < 4; j++) {
                bf16x8_t wf = *(const bf16x8_t*)(qWs + (size_t)((h * 4 + j) * 4 + kc) * 512 + lane * 8);
                acc[j] = MFMA32(wf, xf, acc[j]);
            }
        }
        #pragma unroll
        for (int j = 0; j < 4; j++) {
            float4 bs = *(const float4*)(qb + h * 64 + j * 16 + quad * 4);
            u16x4_t o = pk4((acc[j][0] + bs.x) * sc, (acc[j][1] + bs.y) * sc,
                            (acc[j][2] + bs.z) * sc, (acc[j][3] + bs.w) * sc);
            *(u16x4_t*)(qarea + ((size_t)(qt * 2 + (j >> 1))) * 512 +
                        (((j & 1) * 2 + (quad >> 1)) * 16 + col) * 8 + (quad & 1) * 4) = o;
        }
    }
    bf16x8_t qf[2][2];
    #pragma unroll
    for (int qt = 0; qt < 2; qt++)
        #pragma unroll
        for (int kc = 0; kc < 2; kc++)
            qf[qt][kc] = *(const bf16x8_t*)(qarea + (size_t)(qt * 2 + kc) * 512 + lane * 8);
    __syncthreads();   // everyone's Q in regs; arena free for K/V staging

    // ---- staging setup: wave w owns region w (0:K_h0 1:K_h1 2:V_h0 3:V_h1)
    const int rh = w & 1;
    const int bhr = b * 2 + rh;
    const unsigned short* src0 = (w < 2)
        ? ksw + ((size_t)(bhr * 128 + (1 - mod) * 64) * 2) * 512
        : vls + ((size_t)(bhr * 32 + (1 - mod) * 16) * 8) * 512;
    const int regoff = (w < 2 ? 0 : 16384) + rh * 8192;

    const int bh = b * 2 + h;
    (void)bh;
    const bf16x4_t ones4 = { 0x3F80, 0x3F80, 0x3F80, 0x3F80 };

    f32x4_t O[2][4] = {};
    f32x4_t accl[2] = {};

    // preload kt=0 into regs, write buf0
    bf16x8_t pre[8];
    #pragma unroll
    for (int cc = 0; cc < 8; cc++)
        pre[cc] = *(const bf16x8_t*)(src0 + (size_t)cc * 512 + lane * 8);
    #pragma unroll
    for (int cc = 0; cc < 8; cc++)
        *(bf16x8_t*)(arena + regoff + cc * 1024 + lane * 16) = pre[cc];
    __syncthreads();

    int buf = 0;
    for (int kt = 0; kt < 16; kt++) {
        // prefetch kt+1 into regs (stays in flight over the compute below)
        if (kt < 15) {
            const unsigned short* s = src0 + (size_t)(kt + 1) * 4096 + lane * 8;
            #pragma unroll
            for (int cc = 0; cc < 8; cc++)
                pre[cc] = *(const bf16x8_t*)(s + (size_t)cc * 512);
        }
        // consume current buffer from LDS
        const char* kbase = arena + buf * 32768 + h * 8192;
        const char* vbase = arena + buf * 32768 + 16384 + h * 8192;
        bf16x8_t kf[8];
        #pragma unroll
        for (int i = 0; i < 8; i++)
            kf[i] = *(const bf16x8_t*)(kbase + i * 1024 + lane * 16);
        union { bf16x8_t v8; bf16x4_t v4[2]; } vf[8];
        #pragma unroll
        for (int i = 0; i < 8; i++)
            vf[i].v8 = *(const bf16x8_t*)(vbase + i * 1024 + lane * 16);
        // S^T = K·Q^T
        f32x4_t ST[2][4];
        #pragma unroll
        for (int qt = 0; qt < 2; qt++)
            #pragma unroll
            for (int nb = 0; nb < 4; nb++) {
                f32x4_t sA = {};
                sA = MFMA32(kf[nb * 2 + 0], qf[qt][0], sA);
                sA = MFMA32(kf[nb * 2 + 1], qf[qt][1], sA);
                ST[qt][nb] = sA;
            }
        // exp2 -> P directly in K16 A-operand registers
        bf16x4_t pa[2][4];
        #pragma unroll
        for (int qt = 0; qt < 2; qt++)
            #pragma unroll
            for (int nb = 0; nb < 4; nb++)
                pa[qt][nb] = pk4b(exp2f(ST[qt][nb][0]), exp2f(ST[qt][nb][1]),
                                  exp2f(ST[qt][nb][2]), exp2f(ST[qt][nb][3]));
        #pragma unroll
        for (int qt = 0; qt < 2; qt++) {
            #pragma unroll
            for (int nb = 0; nb < 4; nb++) {
                accl[qt] = MFMA16(pa[qt][nb], ones4, accl[qt]);
                #pragma unroll
                for (int dt = 0; dt < 4; dt++)
                    O[qt][dt] = MFMA16(pa[qt][nb], vf[dt * 2 + (nb >> 1)].v4[nb & 1], O[qt][dt]);
            }
        }
        // write prefetched kt+1 into the other buffer
        if (kt < 15) {
            char* d = arena + (buf ^ 1) * 32768 + regoff;
            #pragma unroll
            for (int cc = 0; cc < 8; cc++)
                *(bf16x8_t*)(d + cc * 1024 + lane * 16) = pre[cc];
        }
        __syncthreads();
        buf ^= 1;
    }

    // ---- epilogue: O rows (query = quad*4+r, d = col) -> sbuf [64 q][136]
    #pragma unroll
    for (int qt = 0; qt < 2; qt++) {
        #pragma unroll
        for (int r = 0; r < 4; r++) {
            float rl = 1.0f / accl[qt][r];
            int qrow = qg * 32 + qt * 16 + quad * 4 + r;
            #pragma unroll
            for (int dt = 0; dt < 4; dt++)
                sbuf[qrow * 136 + h * 64 + dt * 16 + col] = f2bf(O[qt][dt][r] * rl);
        }
    }
    __syncthreads();
    // ---- out-proj: wave w -> q-tile w
    {
        const int qt2 = w;
        bf16x8_t ob[4];
        #pragma unroll
        for (int kc = 0; kc < 4; kc++)
            ob[kc] = *(const bf16x8_t*)(sbuf + (size_t)(qt2 * 16 + col) * 136 + kc * 32 + quad * 8);
        f32x4_t acc[8];
        #pragma unroll
        for (int j = 0; j < 8; j++) acc[j] = f32x4_t{};
        #pragma unroll
        for (int kc = 0; kc < 4; kc++)
            #pragma unroll
            for (int j = 0; j < 8; j++) {
                bf16x8_t wf = *(const bf16x8_t*)(projWs + (size_t)(j * 4 + kc) * 512 + lane * 8);
                acc[j] = MFMA32(wf, ob[kc], acc[j]);
            }
        const int n = b * 8192 + mod * 4096 + blkx * 64 + qt2 * 16 + col;
        #pragma unroll
        for (int j = 0; j < 8; j++) {
            int f0 = j * 16 + quad * 4;
            float4 bs = *(const float4*)(projb + f0);
            float4 o = { acc[j][0] + bs.x, acc[j][1] + bs.y,
                         acc[j][2] + bs.z, acc[j][3] + bs.w };
            *(float4*)(out + (size_t)n * 128 + f0) = o;
        }
    }
}

// ---------------------------------------------------------------------------
extern "C" void kernel_launch(void* const* d_in, const int* in_sizes, int n_in,
                              void* d_out, int out_size, void* d_ws, size_t ws_size,
                              hipStream_t stream) {
    const float* x     = (const float*)d_in[0];
    const float* qW    = (const float*)d_in[1];
    const float* qb    = (const float*)d_in[2];
    const float* kvW   = (const float*)d_in[3];
    const float* kvb   = (const float*)d_in[4];
    const float* projW = (const float*)d_in[5];
    const float* projb = (const float*)d_in[6];
    const float* srW   = (const float*)d_in[7];
    const float* srb   = (const float*)d_in[8];
    const float* lnW   = (const float*)d_in[9];
    const float* lnB   = (const float*)d_in[10];

    char* ws = (char*)d_ws;
    unsigned short* qWs    = (unsigned short*)(ws + 0);         // 32 KB
    unsigned short* kvWs   = (unsigned short*)(ws + 32768);     // 64 KB
    unsigned short* projWs = (unsigned short*)(ws + 98304);     // 32 KB
    unsigned short* srWs   = (unsigned short*)(ws + 131072);    // 128 KB
    unsigned short* ksw    = (unsigned short*)(ws + 262144);    // 2 MB
    unsigned short* vls    = (unsigned short*)(ws + 2359296);   // 2 MB

    k_prep_w<<<dim3(512), dim3(256), 0, stream>>>(qW, kvW, projW, srW,
                                                  qWs, kvWs, projWs, srWs);
    k_convkv<<<dim3(512), dim3(256), 0, stream>>>(x, srWs, srb, lnW, lnB,
                                                  kvWs, kvb, ksw, vls);
    k_attn_f4<<<dim3(64, 2, 4), dim3(256), 0, stream>>>(x, qWs, qb, ksw, vls,
                                                        projWs, projb, (float*)d_out);
}

// Round 9
// 136.859 us; speedup vs baseline: 1.0925x; 1.0800x over previous
//
#include <hip/hip_runtime.h>
#include <hip/hip_bf16.h>

#define LN_EPS 1e-5f

typedef __attribute__((ext_vector_type(8))) short bf16x8_t;
typedef __attribute__((ext_vector_type(4))) short bf16x4_t;
typedef __attribute__((ext_vector_type(4))) float f32x4_t;
typedef __attribute__((ext_vector_type(4))) unsigned short u16x4_t;

#define MFMA32(a, b, c) __builtin_amdgcn_mfma_f32_16x16x32_bf16(a, b, c, 0, 0, 0)
#define MFMA16(a, b, c) __builtin_amdgcn_mfma_f32_16x16x16bf16_1k(a, b, c, 0, 0, 0)

// Guaranteed-native exp2: single v_exp_f32 (quarter-rate), not the OCML
// software routine that plain exp2f may lower to.
__device__ inline float fast_exp2(float x) {
#if __has_builtin(__builtin_amdgcn_exp2f)
    return __builtin_amdgcn_exp2f(x);
#else
    float r;
    asm volatile("v_exp_f32 %0, %1\n\ts_nop 0" : "=v"(r) : "v"(x));
    return r;
#endif
}

__device__ inline unsigned short f2bf(float f) {
    union { float f; unsigned int u; } v; v.f = f;
    unsigned int r = v.u + 0x7fffu + ((v.u >> 16) & 1u);
    return (unsigned short)(r >> 16);
}

__device__ inline u16x4_t pk4(float a, float b, float c, float d) {
    union { u16x4_t v; __hip_bfloat162 h[2]; } u;
    u.h[0] = __float22bfloat162_rn(float2{a, b});
    u.h[1] = __float22bfloat162_rn(float2{c, d});
    return u.v;
}
__device__ inline bf16x4_t pk4b(float a, float b, float c, float d) {
    union { bf16x4_t v; __hip_bfloat162 h[2]; } u;
    u.h[0] = __float22bfloat162_rn(float2{a, b});
    u.h[1] = __float22bfloat162_rn(float2{c, d});
    return u.v;
}
__device__ inline bf16x8_t pk8(float4 a, float4 b) {
    union { bf16x8_t v; __hip_bfloat162 h[4]; } u;
    u.h[0] = __float22bfloat162_rn(float2{a.x, a.y});
    u.h[1] = __float22bfloat162_rn(float2{a.z, a.w});
    u.h[2] = __float22bfloat162_rn(float2{b.x, b.y});
    u.h[3] = __float22bfloat162_rn(float2{b.z, b.w});
    return u.v;
}

// Fragment-layout index for [ROWS][KD] stored as MFMA fragments:
// tile (row>>4, k>>5) = 512 contiguous u16; lane=((k>>3)&3)*16+(row&15), j=k&7.
__device__ inline size_t fragidx(int row, int k, int KC) {
    return ((size_t)((row >> 4) * KC + (k >> 5))) * 512 +
           (((k >> 3) & 3) * 16 + (row & 15)) * 8 + (k & 7);
}

// ---------------------------------------------------------------------------
__global__ void k_prep_w(const float* __restrict__ qW, const float* __restrict__ kvW,
                         const float* __restrict__ projW, const float* __restrict__ srW,
                         unsigned short* __restrict__ qWs, unsigned short* __restrict__ kvWs,
                         unsigned short* __restrict__ projWs, unsigned short* __restrict__ srWs) {
    int i = blockIdx.x * 256 + threadIdx.x;
    if (i < 16384) {
        int n = i & 127, k = i >> 7;
        qWs[fragidx(n, k, 4)] = f2bf(qW[k * 128 + n]);
    } else if (i < 49152) {
        int j = i - 16384; int n = j & 255, k = j >> 8;
        kvWs[fragidx(n, k, 4)] = f2bf(kvW[k * 256 + n]);
    } else if (i < 65536) {
        int j = i - 49152; int n = j & 127, k = j >> 7;
        projWs[fragidx(n, k, 4)] = f2bf(projW[k * 128 + n]);
    } else {
        int j = i - 65536; int n = j >> 9, rem = j & 511, q = rem >> 7, c = rem & 127;
        srWs[fragidx(n, q * 128 + c, 16)] = f2bf(srW[n * 512 + c * 4 + q]);
    }
}

// ---------------------------------------------------------------------------
// Fused SR-conv + bias + LayerNorm + kv-projection (unchanged from R7/R8).
__global__ __launch_bounds__(256)
void k_convkv(const float* __restrict__ x, const unsigned short* __restrict__ srWs,
              const float* __restrict__ srb, const float* __restrict__ lnW,
              const float* __restrict__ lnB, const unsigned short* __restrict__ kvWs,
              const float* __restrict__ kvb, unsigned short* __restrict__ ksw,
              unsigned short* __restrict__ vls) {
    const int t = threadIdx.x, w = t >> 6, lane = t & 63;
    const int col = lane & 15, quad = lane >> 4;
    const int RT = blockIdx.x;

    __shared__ unsigned short xs[4 * 512];
    __shared__ float lnred[4][16][2];

    const int pos = RT * 16 + col;
    const int pb = pos >> 11, phf = (pos >> 10) & 1;
    const int poy = (pos >> 5) & 31, pox = pos & 31;
    int rowbase[4];
    #pragma unroll
    for (int q = 0; q < 4; q++) {
        int ky = q >> 1, kx = q & 1;
        int n = phf * 4096 + (2 * poy + ky) * 64 + 2 * pox + kx;
        rowbase[q] = (pb * 8192 + n) * 128;
    }

    f32x4_t acc[2] = {};
    {
        const unsigned short* wp = srWs + lane * 8;
        #pragma unroll
        for (int kc = 0; kc < 16; kc++) {
            const float* xr = x + rowbase[kc >> 2] + (kc & 3) * 32 + quad * 8;
            float4 xa = *(const float4*)(xr);
            float4 xb2 = *(const float4*)(xr + 4);
            bf16x8_t xb = pk8(xa, xb2);
            #pragma unroll
            for (int jj = 0; jj < 2; jj++) {
                bf16x8_t wf = *(const bf16x8_t*)(wp + (size_t)((w * 2 + jj) * 16 + kc) * 512);
                acc[jj] = MFMA32(wf, xb, acc[jj]);
            }
        }
    }
    float s = 0.f, ss = 0.f;
    #pragma unroll
    for (int jj = 0; jj < 2; jj++) {
        float4 bs = *(const float4*)(srb + (w * 2 + jj) * 16 + quad * 4);
        acc[jj][0] += bs.x; acc[jj][1] += bs.y; acc[jj][2] += bs.z; acc[jj][3] += bs.w;
        #pragma unroll
        for (int r = 0; r < 4; r++) { float v = acc[jj][r]; s += v; ss += v * v; }
    }
    s += __shfl_xor(s, 16, 64);  s += __shfl_xor(s, 32, 64);
    ss += __shfl_xor(ss, 16, 64); ss += __shfl_xor(ss, 32, 64);
    if (lane < 16) { lnred[w][lane][0] = s; lnred[w][lane][1] = ss; }
    __syncthreads();
    float stot = 0.f, sstot = 0.f;
    #pragma unroll
    for (int ww = 0; ww < 4; ww++) { stot += lnred[ww][col][0]; sstot += lnred[ww][col][1]; }
    float mean = stot * (1.0f / 128.0f);
    float var = sstot * (1.0f / 128.0f) - mean * mean;
    float rs = rsqrtf(var + LN_EPS);
    #pragma unroll
    for (int jj = 0; jj < 2; jj++) {
        int f0 = (w * 2 + jj) * 16 + quad * 4;
        float4 g = *(const float4*)(lnW + f0);
        float4 be = *(const float4*)(lnB + f0);
        u16x4_t o = pk4((acc[jj][0] - mean) * rs * g.x + be.x,
                        (acc[jj][1] - mean) * rs * g.y + be.y,
                        (acc[jj][2] - mean) * rs * g.z + be.z,
                        (acc[jj][3] - mean) * rs * g.w + be.w);
        *(u16x4_t*)(xs + ((size_t)(f0 >> 5)) * 512 +
                    (((f0 >> 3) & 3) * 16 + col) * 8 + (f0 & 7)) = o;
    }
    __syncthreads();
    bf16x8_t xf[4];
    #pragma unroll
    for (int kc = 0; kc < 4; kc++)
        xf[kc] = *(const bf16x8_t*)(xs + (size_t)kc * 512 + lane * 8);
    const int p0 = RT * 16;
    const int bb = p0 >> 11;
    #pragma unroll
    for (int jj = 0; jj < 2; jj++) {
        const int nt = w * 2 + jj;
        f32x4_t aK = {};
        #pragma unroll
        for (int kc = 0; kc < 4; kc++) {
            bf16x8_t wf = *(const bf16x8_t*)(kvWs + (size_t)(nt * 4 + kc) * 512 + lane * 8);
            aK = MFMA32(wf, xf[kc], aK);
        }
        float4 bs = *(const float4*)(kvb + nt * 16 + quad * 4);
        int m = (p0 + col) & 2047;
        int bh = bb * 2 + (nt >> 2);
        int d0 = (nt & 3) * 16 + quad * 4;
        u16x4_t o = pk4(aK[0] + bs.x, aK[1] + bs.y, aK[2] + bs.z, aK[3] + bs.w);
        *(u16x4_t*)(ksw + ((size_t)(bh * 128 + (m >> 4)) * 2 + (d0 >> 5)) * 512 +
                    (((d0 >> 3) & 3) * 16 + (m & 15)) * 8 + (d0 & 7)) = o;
    }
    #pragma unroll
    for (int jj = 0; jj < 2; jj++) {
        const int nt = w * 2 + jj;
        f32x4_t aV = {};
        #pragma unroll
        for (int kc = 0; kc < 4; kc++) {
            bf16x8_t wf = *(const bf16x8_t*)(kvWs + (size_t)((8 + nt) * 4 + kc) * 512 + lane * 8);
            aV = MFMA32(xf[kc], wf, aV);
        }
        int fv = nt * 16 + col;
        int h = fv >> 6, dd = fv & 63;
        float bv = kvb[128 + fv];
        int m0 = (p0 + quad * 4) & 2047;
        int bh = bb * 2 + h;
        int kt = m0 >> 6, nb = (m0 >> 4) & 3;
        u16x4_t o = pk4(aV[0] + bv, aV[1] + bv, aV[2] + bv, aV[3] + bv);
        *(u16x4_t*)(vls + (((size_t)(bh * 32 + kt) * 4 + (dd >> 4)) * 2 + (nb >> 1)) * 512 +
                    (quad * 16 + (dd & 15)) * 8 + (nb & 1) * 4) = o;
    }
}

// ---------------------------------------------------------------------------
// Fused q-proj + attention + out-proj (R6 structure: register-resident P via
// K16 MFMA, no LDS in K-loop) with NATIVE v_exp_f32 softmax.
// Block 256 = 4 waves (qg = w&1, h = w>>1); grid (64, 2, 4) = 512 blocks.
__global__ __launch_bounds__(256)
void k_attn_f5(const float* __restrict__ x, const unsigned short* __restrict__ qWs,
               const float* __restrict__ qb, const unsigned short* __restrict__ ksw,
               const unsigned short* __restrict__ vls, const unsigned short* __restrict__ projWs,
               const float* __restrict__ projb, float* __restrict__ out) {
    const int blkx = blockIdx.x, mod = blockIdx.y, b = blockIdx.z;
    const int t = threadIdx.x, w = t >> 6, lane = t & 63;
    const int col = lane & 15, quad = lane >> 4;
    const int qg = w & 1, h = w >> 1;
    const int bh = b * 2 + h;
    const int qbase = mod * 4096 + blkx * 64 + qg * 32;   // within batch b

    __shared__ unsigned short sbuf[64 * 136];   // Q frags (16KB) then O rows

    // ---- q-proj: Q B-frags (scale*log2e folded), wave-local staging
    unsigned short* qarea = sbuf + w * 2048;
    const float sc = 0.125f * 1.44269504089f;
    #pragma unroll
    for (int qt = 0; qt < 2; qt++) {
        const float* xrow = x + ((size_t)b * 8192 + qbase + qt * 16 + col) * 128;
        f32x4_t acc[4] = {};
        #pragma unroll
        for (int kc = 0; kc < 4; kc++) {
            float4 xa = *(const float4*)(xrow + kc * 32 + quad * 8);
            float4 xb2 = *(const float4*)(xrow + kc * 32 + quad * 8 + 4);
            bf16x8_t xf = pk8(xa, xb2);
            #pragma unroll
            for (int j = 0; j < 4; j++) {
                bf16x8_t wf = *(const bf16x8_t*)(qWs + (size_t)((h * 4 + j) * 4 + kc) * 512 + lane * 8);
                acc[j] = MFMA32(wf, xf, acc[j]);
            }
        }
        #pragma unroll
        for (int j = 0; j < 4; j++) {
            float4 bs = *(const float4*)(qb + h * 64 + j * 16 + quad * 4);
            u16x4_t o = pk4((acc[j][0] + bs.x) * sc, (acc[j][1] + bs.y) * sc,
                            (acc[j][2] + bs.z) * sc, (acc[j][3] + bs.w) * sc);
            *(u16x4_t*)(qarea + ((size_t)(qt * 2 + (j >> 1))) * 512 +
                        (((j & 1) * 2 + (quad >> 1)) * 16 + col) * 8 + (quad & 1) * 4) = o;
        }
    }
    bf16x8_t qf[2][2];
    #pragma unroll
    for (int qt = 0; qt < 2; qt++)
        #pragma unroll
        for (int kc = 0; kc < 2; kc++)
            qf[qt][kc] = *(const bf16x8_t*)(qarea + (size_t)(qt * 2 + kc) * 512 + lane * 8);
    __syncthreads();   // Q regs loaded everywhere; sbuf free for O staging

    const unsigned short* kp0 =
        ksw + ((size_t)(bh * 128 + (1 - mod) * 64) * 2) * 512 + lane * 8;
    const unsigned short* vp0 =
        vls + ((size_t)(bh * 32 + (1 - mod) * 16) * 8) * 512 + lane * 8;
    const bf16x4_t ones4 = { 0x3F80, 0x3F80, 0x3F80, 0x3F80 };

    f32x4_t O[2][4] = {};
    f32x4_t accl[2] = {};

    for (int kt = 0; kt < 16; kt++) {
        // K A-frags (8 b128) and V K16-B pairs (8 b128) — contiguous streams
        bf16x8_t kf[8];
        #pragma unroll
        for (int i = 0; i < 8; i++)
            kf[i] = *(const bf16x8_t*)(kp0 + (size_t)(kt * 8 + i) * 512);
        union { bf16x8_t v8; bf16x4_t v4[2]; } vf[8];
        #pragma unroll
        for (int i = 0; i < 8; i++)
            vf[i].v8 = *(const bf16x8_t*)(vp0 + (size_t)(kt * 8 + i) * 512);
        // S^T = K·Q^T
        f32x4_t ST[2][4];
        #pragma unroll
        for (int qt = 0; qt < 2; qt++)
            #pragma unroll
            for (int nb = 0; nb < 4; nb++) {
                f32x4_t sA = {};
                sA = MFMA32(kf[nb * 2 + 0], qf[qt][0], sA);
                sA = MFMA32(kf[nb * 2 + 1], qf[qt][1], sA);
                ST[qt][nb] = sA;
            }
        // native exp2 -> P directly in K16 A-operand registers (no LDS)
        bf16x4_t pa[2][4];
        #pragma unroll
        for (int qt = 0; qt < 2; qt++)
            #pragma unroll
            for (int nb = 0; nb < 4; nb++)
                pa[qt][nb] = pk4b(fast_exp2(ST[qt][nb][0]), fast_exp2(ST[qt][nb][1]),
                                  fast_exp2(ST[qt][nb][2]), fast_exp2(ST[qt][nb][3]));
        // l accumulate (B=ones) and O += P·V
        #pragma unroll
        for (int qt = 0; qt < 2; qt++) {
            #pragma unroll
            for (int nb = 0; nb < 4; nb++) {
                accl[qt] = MFMA16(pa[qt][nb], ones4, accl[qt]);
                #pragma unroll
                for (int dt = 0; dt < 4; dt++)
                    O[qt][dt] = MFMA16(pa[qt][nb], vf[dt * 2 + (nb >> 1)].v4[nb & 1], O[qt][dt]);
            }
        }
    }

    // ---- epilogue: O rows (query=quad*4+r, d=col) -> sbuf [64 q][136]
    #pragma unroll
    for (int qt = 0; qt < 2; qt++) {
        #pragma unroll
        for (int r = 0; r < 4; r++) {
            float rl = 1.0f / accl[qt][r];
            int qrow = qg * 32 + qt * 16 + quad * 4 + r;
            #pragma unroll
            for (int dt = 0; dt < 4; dt++)
                sbuf[qrow * 136 + h * 64 + dt * 16 + col] = f2bf(O[qt][dt][r] * rl);
        }
    }
    __syncthreads();
    // ---- out-proj: wave w -> q-tile w
    {
        const int qt2 = w;
        bf16x8_t ob[4];
        #pragma unroll
        for (int kc = 0; kc < 4; kc++)
            ob[kc] = *(const bf16x8_t*)(sbuf + (size_t)(qt2 * 16 + col) * 136 + kc * 32 + quad * 8);
        f32x4_t acc[8];
        #pragma unroll
        for (int j = 0; j < 8; j++) acc[j] = f32x4_t{};
        #pragma unroll
        for (int kc = 0; kc < 4; kc++)
            #pragma unroll
            for (int j = 0; j < 8; j++) {
                bf16x8_t wf = *(const bf16x8_t*)(projWs + (size_t)(j * 4 + kc) * 512 + lane * 8);
                acc[j] = MFMA32(wf, ob[kc], acc[j]);
            }
        const int n = b * 8192 + mod * 4096 + blkx * 64 + qt2 * 16 + col;
        #pragma unroll
        for (int j = 0; j < 8; j++) {
            int f0 = j * 16 + quad * 4;
            float4 bs = *(const float4*)(projb + f0);
            float4 o = { acc[j][0] + bs.x, acc[j][1] + bs.y,
                         acc[j][2] + bs.z, acc[j][3] + bs.w };
            *(float4*)(out + (size_t)n * 128 + f0) = o;
        }
    }
}

// ---------------------------------------------------------------------------
extern "C" void kernel_launch(void* const* d_in, const int* in_sizes, int n_in,
                              void* d_out, int out_size, void* d_ws, size_t ws_size,
                              hipStream_t stream) {
    const float* x     = (const float*)d_in[0];
    const float* qW    = (const float*)d_in[1];
    const float* qb    = (const float*)d_in[2];
    const float* kvW   = (const float*)d_in[3];
    const float* kvb   = (const float*)d_in[4];
    const float* projW = (const float*)d_in[5];
    const float* projb = (const float*)d_in[6];
    const float* srW   = (const float*)d_in[7];
    const float* srb   = (const float*)d_in[8];
    const float* lnW   = (const float*)d_in[9];
    const float* lnB   = (const float*)d_in[10];

    char* ws = (char*)d_ws;
    unsigned short* qWs    = (unsigned short*)(ws + 0);         // 32 KB
    unsigned short* kvWs   = (unsigned short*)(ws + 32768);     // 64 KB
    unsigned short* projWs = (unsigned short*)(ws + 98304);     // 32 KB
    unsigned short* srWs   = (unsigned short*)(ws + 131072);    // 128 KB
    unsigned short* ksw    = (unsigned short*)(ws + 262144);    // 2 MB
    unsigned short* vls    = (unsigned short*)(ws + 2359296);   // 2 MB

    k_prep_w<<<dim3(512), dim3(256), 0, stream>>>(qW, kvW, projW, srW,
                                                  qWs, kvWs, projWs, srWs);
    k_convkv<<<dim3(512), dim3(256), 0, stream>>>(x, srWs, srb, lnW, lnB,
                                                  kvWs, kvb, ksw, vls);
    k_attn_f5<<<dim3(64, 2, 4), dim3(256), 0, stream>>>(x, qWs, qb, ksw, vls,
                                                        projWs, projb, (float*)d_out);
}

// Round 10
// 133.842 us; speedup vs baseline: 1.1171x; 1.0225x over previous
//
#include <hip/hip_runtime.h>
#include <hip/hip_bf16.h>

#define LN_EPS 1e-5f

typedef __attribute__((ext_vector_type(8))) short bf16x8_t;
typedef __attribute__((ext_vector_type(4))) short bf16x4_t;
typedef __attribute__((ext_vector_type(4))) float f32x4_t;
typedef __attribute__((ext_vector_type(4))) unsigned short u16x4_t;

#define MFMA32(a, b, c) __builtin_amdgcn_mfma_f32_16x16x32_bf16(a, b, c, 0, 0, 0)
#define MFMA16(a, b, c) __builtin_amdgcn_mfma_f32_16x16x16bf16_1k(a, b, c, 0, 0, 0)

// Guaranteed-native exp2 (single v_exp_f32) — verified win in R9.
__device__ inline float fast_exp2(float x) {
#if __has_builtin(__builtin_amdgcn_exp2f)
    return __builtin_amdgcn_exp2f(x);
#else
    float r;
    asm volatile("v_exp_f32 %0, %1\n\ts_nop 0" : "=v"(r) : "v"(x));
    return r;
#endif
}

__device__ inline unsigned short f2bf(float f) {
    union { float f; unsigned int u; } v; v.f = f;
    unsigned int r = v.u + 0x7fffu + ((v.u >> 16) & 1u);
    return (unsigned short)(r >> 16);
}

__device__ inline u16x4_t pk4(float a, float b, float c, float d) {
    union { u16x4_t v; __hip_bfloat162 h[2]; } u;
    u.h[0] = __float22bfloat162_rn(float2{a, b});
    u.h[1] = __float22bfloat162_rn(float2{c, d});
    return u.v;
}
__device__ inline bf16x4_t pk4b(float a, float b, float c, float d) {
    union { bf16x4_t v; __hip_bfloat162 h[2]; } u;
    u.h[0] = __float22bfloat162_rn(float2{a, b});
    u.h[1] = __float22bfloat162_rn(float2{c, d});
    return u.v;
}
__device__ inline bf16x8_t pk8(float4 a, float4 b) {
    union { bf16x8_t v; __hip_bfloat162 h[4]; } u;
    u.h[0] = __float22bfloat162_rn(float2{a.x, a.y});
    u.h[1] = __float22bfloat162_rn(float2{a.z, a.w});
    u.h[2] = __float22bfloat162_rn(float2{b.x, b.y});
    u.h[3] = __float22bfloat162_rn(float2{b.z, b.w});
    return u.v;
}

// Fragment-layout index for [ROWS][KD] stored as MFMA fragments:
// tile (row>>4, k>>5) = 512 contiguous u16; lane=((k>>3)&3)*16+(row&15), j=k&7.
__device__ inline size_t fragidx(int row, int k, int KC) {
    return ((size_t)((row >> 4) * KC + (k >> 5))) * 512 +
           (((k >> 3) & 3) * 16 + (row & 15)) * 8 + (k & 7);
}

// ---------------------------------------------------------------------------
__global__ void k_prep_w(const float* __restrict__ qW, const float* __restrict__ kvW,
                         const float* __restrict__ projW, const float* __restrict__ srW,
                         unsigned short* __restrict__ qWs, unsigned short* __restrict__ kvWs,
                         unsigned short* __restrict__ projWs, unsigned short* __restrict__ srWs) {
    int i = blockIdx.x * 256 + threadIdx.x;
    if (i < 16384) {
        int n = i & 127, k = i >> 7;
        qWs[fragidx(n, k, 4)] = f2bf(qW[k * 128 + n]);
    } else if (i < 49152) {
        int j = i - 16384; int n = j & 255, k = j >> 8;
        kvWs[fragidx(n, k, 4)] = f2bf(kvW[k * 256 + n]);
    } else if (i < 65536) {
        int j = i - 49152; int n = j & 127, k = j >> 7;
        projWs[fragidx(n, k, 4)] = f2bf(projW[k * 128 + n]);
    } else {
        int j = i - 65536; int n = j >> 9, rem = j & 511, q = rem >> 7, c = rem & 127;
        srWs[fragidx(n, q * 128 + c, 16)] = f2bf(srW[n * 512 + c * 4 + q]);
    }
}

// ---------------------------------------------------------------------------
// Fused SR-conv + bias + LayerNorm + kv-projection.
// NEW: x-footprint (two contiguous 32-row chunks) staged into LDS via
// coalesced float4 loads; conv loop reads LDS (was 16-line global gathers).
#define XPAD 132
__global__ __launch_bounds__(256)
void k_convkv(const float* __restrict__ x, const unsigned short* __restrict__ srWs,
              const float* __restrict__ srb, const float* __restrict__ lnW,
              const float* __restrict__ lnB, const unsigned short* __restrict__ kvWs,
              const float* __restrict__ kvb, unsigned short* __restrict__ ksw,
              unsigned short* __restrict__ vls) {
    const int t = threadIdx.x, w = t >> 6, lane = t & 63;
    const int col = lane & 15, quad = lane >> 4;
    const int RT = blockIdx.x;                 // row-tile 0..511

    __shared__ unsigned short xl[64 * XPAD];   // staged x rows (bf16), ~16.9 KB
    __shared__ unsigned short xs[4 * 512];
    __shared__ float lnred[4][16][2];

    // geometry: positions p = RT*16 + col share pb/phf/oy; ox = ox0 + col
    const int pb = RT >> 7, phf = (RT >> 6) & 1;
    const int oy = (RT >> 1) & 31, ox0 = (RT & 1) * 16;
    // stage two 32-row chunks: n0 + chunk*64 + rr, rr in [0,32)
    const int n0 = phf * 4096 + 2 * oy * 64 + 2 * ox0;
    #pragma unroll
    for (int it = 0; it < 8; it++) {
        int idx = it * 256 + t;                // 0..2047 float4s
        int chunk = idx >> 10;
        int rr = (idx >> 5) & 31;
        int c4 = idx & 31;
        float4 v = *(const float4*)(x + ((size_t)(pb * 8192 + n0 + chunk * 64 + rr)) * 128 + c4 * 4);
        *(u16x4_t*)(xl + (chunk * 32 + rr) * XPAD + c4 * 4) = pk4(v.x, v.y, v.z, v.w);
    }
    __syncthreads();

    // conv (transposed): wave w computes feature-tiles {2w, 2w+1}
    f32x4_t acc[2] = {};
    {
        const unsigned short* wp = srWs + lane * 8;
        #pragma unroll
        for (int kc = 0; kc < 16; kc++) {
            const int q = kc >> 2, cg = kc & 3;
            const int r = (q >> 1) * 32 + 2 * col + (q & 1);
            bf16x8_t xb = *(const bf16x8_t*)(xl + r * XPAD + cg * 32 + quad * 8);
            #pragma unroll
            for (int jj = 0; jj < 2; jj++) {
                bf16x8_t wf = *(const bf16x8_t*)(wp + (size_t)((w * 2 + jj) * 16 + kc) * 512);
                acc[jj] = MFMA32(wf, xb, acc[jj]);
            }
        }
    }
    // + bias, moments
    float s = 0.f, ss = 0.f;
    #pragma unroll
    for (int jj = 0; jj < 2; jj++) {
        float4 bs = *(const float4*)(srb + (w * 2 + jj) * 16 + quad * 4);
        acc[jj][0] += bs.x; acc[jj][1] += bs.y; acc[jj][2] += bs.z; acc[jj][3] += bs.w;
        #pragma unroll
        for (int r = 0; r < 4; r++) { float v = acc[jj][r]; s += v; ss += v * v; }
    }
    s += __shfl_xor(s, 16, 64);  s += __shfl_xor(s, 32, 64);
    ss += __shfl_xor(ss, 16, 64); ss += __shfl_xor(ss, 32, 64);
    if (lane < 16) { lnred[w][lane][0] = s; lnred[w][lane][1] = ss; }
    __syncthreads();
    float stot = 0.f, sstot = 0.f;
    #pragma unroll
    for (int ww = 0; ww < 4; ww++) { stot += lnred[ww][col][0]; sstot += lnred[ww][col][1]; }
    float mean = stot * (1.0f / 128.0f);
    float var = sstot * (1.0f / 128.0f) - mean * mean;
    float rs = rsqrtf(var + LN_EPS);
    #pragma unroll
    for (int jj = 0; jj < 2; jj++) {
        int f0 = (w * 2 + jj) * 16 + quad * 4;
        float4 g = *(const float4*)(lnW + f0);
        float4 be = *(const float4*)(lnB + f0);
        u16x4_t o = pk4((acc[jj][0] - mean) * rs * g.x + be.x,
                        (acc[jj][1] - mean) * rs * g.y + be.y,
                        (acc[jj][2] - mean) * rs * g.z + be.z,
                        (acc[jj][3] - mean) * rs * g.w + be.w);
        *(u16x4_t*)(xs + ((size_t)(f0 >> 5)) * 512 +
                    (((f0 >> 3) & 3) * 16 + col) * 8 + (f0 & 7)) = o;
    }
    __syncthreads();
    bf16x8_t xf[4];
    #pragma unroll
    for (int kc = 0; kc < 4; kc++)
        xf[kc] = *(const bf16x8_t*)(xs + (size_t)kc * 512 + lane * 8);
    const int p0 = RT * 16;
    const int bb = p0 >> 11;
    // K (transposed): feature-tiles {2w, 2w+1}
    #pragma unroll
    for (int jj = 0; jj < 2; jj++) {
        const int nt = w * 2 + jj;
        f32x4_t aK = {};
        #pragma unroll
        for (int kc = 0; kc < 4; kc++) {
            bf16x8_t wf = *(const bf16x8_t*)(kvWs + (size_t)(nt * 4 + kc) * 512 + lane * 8);
            aK = MFMA32(wf, xf[kc], aK);
        }
        float4 bs = *(const float4*)(kvb + nt * 16 + quad * 4);
        int m = (p0 + col) & 2047;
        int bh = bb * 2 + (nt >> 2);
        int d0 = (nt & 3) * 16 + quad * 4;
        u16x4_t o = pk4(aK[0] + bs.x, aK[1] + bs.y, aK[2] + bs.z, aK[3] + bs.w);
        *(u16x4_t*)(ksw + ((size_t)(bh * 128 + (m >> 4)) * 2 + (d0 >> 5)) * 512 +
                    (((d0 >> 3) & 3) * 16 + (m & 15)) * 8 + (d0 & 7)) = o;
    }
    // V (normal): feature-tiles {2w, 2w+1} of V's 8 -> vls K16-B layout
    #pragma unroll
    for (int jj = 0; jj < 2; jj++) {
        const int nt = w * 2 + jj;
        f32x4_t aV = {};
        #pragma unroll
        for (int kc = 0; kc < 4; kc++) {
            bf16x8_t wf = *(const bf16x8_t*)(kvWs + (size_t)((8 + nt) * 4 + kc) * 512 + lane * 8);
            aV = MFMA32(xf[kc], wf, aV);
        }
        int fv = nt * 16 + col;
        int h = fv >> 6, dd = fv & 63;
        float bv = kvb[128 + fv];
        int m0 = (p0 + quad * 4) & 2047;
        int bh = bb * 2 + h;
        int kt = m0 >> 6, nb = (m0 >> 4) & 3;
        u16x4_t o = pk4(aV[0] + bv, aV[1] + bv, aV[2] + bv, aV[3] + bv);
        *(u16x4_t*)(vls + (((size_t)(bh * 32 + kt) * 4 + (dd >> 4)) * 2 + (nb >> 1)) * 512 +
                    (quad * 16 + (dd & 15)) * 8 + (nb & 1) * 4) = o;
    }
}

// ---------------------------------------------------------------------------
// Fused q-proj + attention + out-proj. R9 structure (register P, native exp2)
// + NEW: explicit 2-deep register double-buffer of K/V, unrolled x2 so buffer
// selection is static. Loads for kt+1 issue before kt's exp/PV -> L2 latency
// hidden inside the wave. Block 256 = 4 waves (qg=w&1, h=w>>1); grid (64,2,4).
__global__ __launch_bounds__(256, 2)
void k_attn_f6(const float* __restrict__ x, const unsigned short* __restrict__ qWs,
               const float* __restrict__ qb, const unsigned short* __restrict__ ksw,
               const unsigned short* __restrict__ vls, const unsigned short* __restrict__ projWs,
               const float* __restrict__ projb, float* __restrict__ out) {
    const int blkx = blockIdx.x, mod = blockIdx.y, b = blockIdx.z;
    const int t = threadIdx.x, w = t >> 6, lane = t & 63;
    const int col = lane & 15, quad = lane >> 4;
    const int qg = w & 1, h = w >> 1;
    const int bh = b * 2 + h;
    const int qbase = mod * 4096 + blkx * 64 + qg * 32;

    __shared__ unsigned short sbuf[64 * 136];   // Q frags (16KB) then O rows

    // ---- q-proj: Q B-frags (scale*log2e folded), wave-local staging
    unsigned short* qarea = sbuf + w * 2048;
    const float sc = 0.125f * 1.44269504089f;
    #pragma unroll
    for (int qt = 0; qt < 2; qt++) {
        const float* xrow = x + ((size_t)b * 8192 + qbase + qt * 16 + col) * 128;
        f32x4_t acc[4] = {};
        #pragma unroll
        for (int kc = 0; kc < 4; kc++) {
            float4 xa = *(const float4*)(xrow + kc * 32 + quad * 8);
            float4 xb2 = *(const float4*)(xrow + kc * 32 + quad * 8 + 4);
            bf16x8_t xf = pk8(xa, xb2);
            #pragma unroll
            for (int j = 0; j < 4; j++) {
                bf16x8_t wf = *(const bf16x8_t*)(qWs + (size_t)((h * 4 + j) * 4 + kc) * 512 + lane * 8);
                acc[j] = MFMA32(wf, xf, acc[j]);
            }
        }
        #pragma unroll
        for (int j = 0; j < 4; j++) {
            float4 bs = *(const float4*)(qb + h * 64 + j * 16 + quad * 4);
            u16x4_t o = pk4((acc[j][0] + bs.x) * sc, (acc[j][1] + bs.y) * sc,
                            (acc[j][2] + bs.z) * sc, (acc[j][3] + bs.w) * sc);
            *(u16x4_t*)(qarea + ((size_t)(qt * 2 + (j >> 1))) * 512 +
                        (((j & 1) * 2 + (quad >> 1)) * 16 + col) * 8 + (quad & 1) * 4) = o;
        }
    }
    bf16x8_t qf[2][2];
    #pragma unroll
    for (int qt = 0; qt < 2; qt++)
        #pragma unroll
        for (int kc = 0; kc < 2; kc++)
            qf[qt][kc] = *(const bf16x8_t*)(qarea + (size_t)(qt * 2 + kc) * 512 + lane * 8);
    __syncthreads();   // Q regs loaded everywhere; sbuf free for O staging

    const unsigned short* kp0 =
        ksw + ((size_t)(bh * 128 + (1 - mod) * 64) * 2) * 512 + lane * 8;
    const unsigned short* vp0 =
        vls + ((size_t)(bh * 32 + (1 - mod) * 16) * 8) * 512 + lane * 8;
    const bf16x4_t ones4 = { 0x3F80, 0x3F80, 0x3F80, 0x3F80 };

    f32x4_t O[2][4] = {};
    f32x4_t accl[2] = {};

    union vun { bf16x8_t v8; bf16x4_t v4[2]; };
    bf16x8_t kf0[8], kf1[8];
    vun vf0[8], vf1[8];

    auto pref0 = [&](int kt) {
        #pragma unroll
        for (int i = 0; i < 8; i++) {
            kf0[i] = *(const bf16x8_t*)(kp0 + (size_t)(kt * 8 + i) * 512);
            vf0[i].v8 = *(const bf16x8_t*)(vp0 + (size_t)(kt * 8 + i) * 512);
        }
    };
    auto pref1 = [&](int kt) {
        #pragma unroll
        for (int i = 0; i < 8; i++) {
            kf1[i] = *(const bf16x8_t*)(kp0 + (size_t)(kt * 8 + i) * 512);
            vf1[i].v8 = *(const bf16x8_t*)(vp0 + (size_t)(kt * 8 + i) * 512);
        }
    };
    auto body = [&](bf16x8_t (&kfc)[8], vun (&vfc)[8]) {
        f32x4_t ST[2][4];
        #pragma unroll
        for (int qt = 0; qt < 2; qt++)
            #pragma unroll
            for (int nb = 0; nb < 4; nb++) {
                f32x4_t sA = {};
                sA = MFMA32(kfc[nb * 2 + 0], qf[qt][0], sA);
                sA = MFMA32(kfc[nb * 2 + 1], qf[qt][1], sA);
                ST[qt][nb] = sA;
            }
        bf16x4_t pa[2][4];
        #pragma unroll
        for (int qt = 0; qt < 2; qt++)
            #pragma unroll
            for (int nb = 0; nb < 4; nb++)
                pa[qt][nb] = pk4b(fast_exp2(ST[qt][nb][0]), fast_exp2(ST[qt][nb][1]),
                                  fast_exp2(ST[qt][nb][2]), fast_exp2(ST[qt][nb][3]));
        #pragma unroll
        for (int qt = 0; qt < 2; qt++) {
            #pragma unroll
            for (int nb = 0; nb < 4; nb++) {
                accl[qt] = MFMA16(pa[qt][nb], ones4, accl[qt]);
                #pragma unroll
                for (int dt = 0; dt < 4; dt++)
                    O[qt][dt] = MFMA16(pa[qt][nb], vfc[dt * 2 + (nb >> 1)].v4[nb & 1], O[qt][dt]);
            }
        }
    };

    pref0(0);
    #pragma unroll
    for (int kt2 = 0; kt2 < 8; kt2++) {
        pref1(kt2 * 2 + 1);          // loads in flight across body(kf0)
        body(kf0, vf0);
        if (kt2 < 7) pref0(kt2 * 2 + 2);  // loads in flight across body(kf1)
        body(kf1, vf1);
    }

    // ---- epilogue: O rows (query=quad*4+r, d=col) -> sbuf [64 q][136]
    #pragma unroll
    for (int qt = 0; qt < 2; qt++) {
        #pragma unroll
        for (int r = 0; r < 4; r++) {
            float rl = 1.0f / accl[qt][r];
            int qrow = qg * 32 + qt * 16 + quad * 4 + r;
            #pragma unroll
            for (int dt = 0; dt < 4; dt++)
                sbuf[qrow * 136 + h * 64 + dt * 16 + col] = f2bf(O[qt][dt][r] * rl);
        }
    }
    __syncthreads();
    // ---- out-proj: wave w -> q-tile w
    {
        const int qt2 = w;
        bf16x8_t ob[4];
        #pragma unroll
        for (int kc = 0; kc < 4; kc++)
            ob[kc] = *(const bf16x8_t*)(sbuf + (size_t)(qt2 * 16 + col) * 136 + kc * 32 + quad * 8);
        f32x4_t acc[8];
        #pragma unroll
        for (int j = 0; j < 8; j++) acc[j] = f32x4_t{};
        #pragma unroll
        for (int kc = 0; kc < 4; kc++)
            #pragma unroll
            for (int j = 0; j < 8; j++) {
                bf16x8_t wf = *(const bf16x8_t*)(projWs + (size_t)(j * 4 + kc) * 512 + lane * 8);
                acc[j] = MFMA32(wf, ob[kc], acc[j]);
            }
        const int n = b * 8192 + mod * 4096 + blkx * 64 + qt2 * 16 + col;
        #pragma unroll
        for (int j = 0; j < 8; j++) {
            int f0 = j * 16 + quad * 4;
            float4 bs = *(const float4*)(projb + f0);
            float4 o = { acc[j][0] + bs.x, acc[j][1] + bs.y,
                         acc[j][2] + bs.z, acc[j][3] + bs.w };
            *(float4*)(out + (size_t)n * 128 + f0) = o;
        }
    }
}

// ---------------------------------------------------------------------------
extern "C" void kernel_launch(void* const* d_in, const int* in_sizes, int n_in,
                              void* d_out, int out_size, void* d_ws, size_t ws_size,
                              hipStream_t stream) {
    const float* x     = (const float*)d_in[0];
    const float* qW    = (const float*)d_in[1];
    const float* qb    = (const float*)d_in[2];
    const float* kvW   = (const float*)d_in[3];
    const float* kvb   = (const float*)d_in[4];
    const float* projW = (const float*)d_in[5];
    const float* projb = (const float*)d_in[6];
    const float* srW   = (const float*)d_in[7];
    const float* srb   = (const float*)d_in[8];
    const float* lnW   = (const float*)d_in[9];
    const float* lnB   = (const float*)d_in[10];

    char* ws = (char*)d_ws;
    unsigned short* qWs    = (unsigned short*)(ws + 0);         // 32 KB
    unsigned short* kvWs   = (unsigned short*)(ws + 32768);     // 64 KB
    unsigned short* projWs = (unsigned short*)(ws + 98304);     // 32 KB
    unsigned short* srWs   = (unsigned short*)(ws + 131072);    // 128 KB
    unsigned short* ksw    = (unsigned short*)(ws + 262144);    // 2 MB
    unsigned short* vls    = (unsigned short*)(ws + 2359296);   // 2 MB

    k_prep_w<<<dim3(512), dim3(256), 0, stream>>>(qW, kvW, projW, srW,
                                                  qWs, kvWs, projWs, srWs);
    k_convkv<<<dim3(512), dim3(256), 0, stream>>>(x, srWs, srb, lnW, lnB,
                                                  kvWs, kvb, ksw, vls);
    k_attn_f6<<<dim3(64, 2, 4), dim3(256), 0, stream>>>(x, qWs, qb, ksw, vls,
                                                        projWs, projb, (float*)d_out);
}

// Round 11
// 132.316 us; speedup vs baseline: 1.1300x; 1.0115x over previous
//
#include <hip/hip_runtime.h>
#include <hip/hip_bf16.h>

#define LN_EPS 1e-5f

typedef __attribute__((ext_vector_type(8))) short bf16x8_t;
typedef __attribute__((ext_vector_type(4))) float f32x4_t;
typedef __attribute__((ext_vector_type(4))) unsigned short u16x4_t;

#define MFMA32(a, b, c) __builtin_amdgcn_mfma_f32_16x16x32_bf16(a, b, c, 0, 0, 0)

// Guaranteed-native exp2 (single v_exp_f32) — verified win in R9.
__device__ inline float fast_exp2(float x) {
#if __has_builtin(__builtin_amdgcn_exp2f)
    return __builtin_amdgcn_exp2f(x);
#else
    float r;
    asm volatile("v_exp_f32 %0, %1\n\ts_nop 0" : "=v"(r) : "v"(x));
    return r;
#endif
}

__device__ inline unsigned short f2bf(float f) {
    union { float f; unsigned int u; } v; v.f = f;
    unsigned int r = v.u + 0x7fffu + ((v.u >> 16) & 1u);
    return (unsigned short)(r >> 16);
}

__device__ inline u16x4_t pk4(float a, float b, float c, float d) {
    union { u16x4_t v; __hip_bfloat162 h[2]; } u;
    u.h[0] = __float22bfloat162_rn(float2{a, b});
    u.h[1] = __float22bfloat162_rn(float2{c, d});
    return u.v;
}
__device__ inline bf16x8_t pk8(float4 a, float4 b) {
    union { bf16x8_t v; __hip_bfloat162 h[4]; } u;
    u.h[0] = __float22bfloat162_rn(float2{a.x, a.y});
    u.h[1] = __float22bfloat162_rn(float2{a.z, a.w});
    u.h[2] = __float22bfloat162_rn(float2{b.x, b.y});
    u.h[3] = __float22bfloat162_rn(float2{b.z, b.w});
    return u.v;
}

// Fragment-layout index for [ROWS][KD] stored as MFMA fragments:
// tile (row>>4, k>>5) = 512 contiguous u16; lane=((k>>3)&3)*16+(row&15), j=k&7.
__device__ inline size_t fragidx(int row, int k, int KC) {
    return ((size_t)((row >> 4) * KC + (k >> 5))) * 512 +
           (((k >> 3) & 3) * 16 + (row & 15)) * 8 + (k & 7);
}

// ---------------------------------------------------------------------------
__global__ void k_prep_w(const float* __restrict__ qW, const float* __restrict__ kvW,
                         const float* __restrict__ projW, const float* __restrict__ srW,
                         unsigned short* __restrict__ qWs, unsigned short* __restrict__ kvWs,
                         unsigned short* __restrict__ projWs, unsigned short* __restrict__ srWs) {
    int i = blockIdx.x * 256 + threadIdx.x;
    if (i < 16384) {
        int n = i & 127, k = i >> 7;
        qWs[fragidx(n, k, 4)] = f2bf(qW[k * 128 + n]);
    } else if (i < 49152) {
        int j = i - 16384; int n = j & 255, k = j >> 8;
        kvWs[fragidx(n, k, 4)] = f2bf(kvW[k * 256 + n]);
    } else if (i < 65536) {
        int j = i - 49152; int n = j & 127, k = j >> 7;
        projWs[fragidx(n, k, 4)] = f2bf(projW[k * 128 + n]);
    } else {
        int j = i - 65536; int n = j >> 9, rem = j & 511, q = rem >> 7, c = rem & 127;
        srWs[fragidx(n, q * 128 + c, 16)] = f2bf(srW[n * 512 + c * 4 + q]);
    }
}

// ---------------------------------------------------------------------------
// Fused SR-conv + bias + LayerNorm + kv-projection. R10 LDS x-staging kept.
// NEW: V stored in K32 MFMA B-operand tiles: vls[bh][32 kt][4 dt][2 t][512],
// tile = B[k=key32][n=d16], element at (quad_b*16 + d)*8 + j  (k=quad_b*8+j).
#define XPAD 132
__global__ __launch_bounds__(256)
void k_convkv(const float* __restrict__ x, const unsigned short* __restrict__ srWs,
              const float* __restrict__ srb, const float* __restrict__ lnW,
              const float* __restrict__ lnB, const unsigned short* __restrict__ kvWs,
              const float* __restrict__ kvb, unsigned short* __restrict__ ksw,
              unsigned short* __restrict__ vls) {
    const int t = threadIdx.x, w = t >> 6, lane = t & 63;
    const int col = lane & 15, quad = lane >> 4;
    const int RT = blockIdx.x;                 // row-tile 0..511

    __shared__ unsigned short xl[64 * XPAD];
    __shared__ unsigned short xs[4 * 512];
    __shared__ float lnred[4][16][2];

    const int pb = RT >> 7, phf = (RT >> 6) & 1;
    const int oy = (RT >> 1) & 31, ox0 = (RT & 1) * 16;
    const int n0 = phf * 4096 + 2 * oy * 64 + 2 * ox0;
    #pragma unroll
    for (int it = 0; it < 8; it++) {
        int idx = it * 256 + t;
        int chunk = idx >> 10;
        int rr = (idx >> 5) & 31;
        int c4 = idx & 31;
        float4 v = *(const float4*)(x + ((size_t)(pb * 8192 + n0 + chunk * 64 + rr)) * 128 + c4 * 4);
        *(u16x4_t*)(xl + (chunk * 32 + rr) * XPAD + c4 * 4) = pk4(v.x, v.y, v.z, v.w);
    }
    __syncthreads();

    f32x4_t acc[2] = {};
    {
        const unsigned short* wp = srWs + lane * 8;
        #pragma unroll
        for (int kc = 0; kc < 16; kc++) {
            const int q = kc >> 2, cg = kc & 3;
            const int r = (q >> 1) * 32 + 2 * col + (q & 1);
            bf16x8_t xb = *(const bf16x8_t*)(xl + r * XPAD + cg * 32 + quad * 8);
            #pragma unroll
            for (int jj = 0; jj < 2; jj++) {
                bf16x8_t wf = *(const bf16x8_t*)(wp + (size_t)((w * 2 + jj) * 16 + kc) * 512);
                acc[jj] = MFMA32(wf, xb, acc[jj]);
            }
        }
    }
    float s = 0.f, ss = 0.f;
    #pragma unroll
    for (int jj = 0; jj < 2; jj++) {
        float4 bs = *(const float4*)(srb + (w * 2 + jj) * 16 + quad * 4);
        acc[jj][0] += bs.x; acc[jj][1] += bs.y; acc[jj][2] += bs.z; acc[jj][3] += bs.w;
        #pragma unroll
        for (int r = 0; r < 4; r++) { float v = acc[jj][r]; s += v; ss += v * v; }
    }
    s += __shfl_xor(s, 16, 64);  s += __shfl_xor(s, 32, 64);
    ss += __shfl_xor(ss, 16, 64); ss += __shfl_xor(ss, 32, 64);
    if (lane < 16) { lnred[w][lane][0] = s; lnred[w][lane][1] = ss; }
    __syncthreads();
    float stot = 0.f, sstot = 0.f;
    #pragma unroll
    for (int ww = 0; ww < 4; ww++) { stot += lnred[ww][col][0]; sstot += lnred[ww][col][1]; }
    float mean = stot * (1.0f / 128.0f);
    float var = sstot * (1.0f / 128.0f) - mean * mean;
    float rs = rsqrtf(var + LN_EPS);
    #pragma unroll
    for (int jj = 0; jj < 2; jj++) {
        int f0 = (w * 2 + jj) * 16 + quad * 4;
        float4 g = *(const float4*)(lnW + f0);
        float4 be = *(const float4*)(lnB + f0);
        u16x4_t o = pk4((acc[jj][0] - mean) * rs * g.x + be.x,
                        (acc[jj][1] - mean) * rs * g.y + be.y,
                        (acc[jj][2] - mean) * rs * g.z + be.z,
                        (acc[jj][3] - mean) * rs * g.w + be.w);
        *(u16x4_t*)(xs + ((size_t)(f0 >> 5)) * 512 +
                    (((f0 >> 3) & 3) * 16 + col) * 8 + (f0 & 7)) = o;
    }
    __syncthreads();
    bf16x8_t xf[4];
    #pragma unroll
    for (int kc = 0; kc < 4; kc++)
        xf[kc] = *(const bf16x8_t*)(xs + (size_t)kc * 512 + lane * 8);
    const int p0 = RT * 16;
    const int bb = p0 >> 11;
    // K (transposed): feature-tiles {2w, 2w+1}
    #pragma unroll
    for (int jj = 0; jj < 2; jj++) {
        const int nt = w * 2 + jj;
        f32x4_t aK = {};
        #pragma unroll
        for (int kc = 0; kc < 4; kc++) {
            bf16x8_t wf = *(const bf16x8_t*)(kvWs + (size_t)(nt * 4 + kc) * 512 + lane * 8);
            aK = MFMA32(wf, xf[kc], aK);
        }
        float4 bs = *(const float4*)(kvb + nt * 16 + quad * 4);
        int m = (p0 + col) & 2047;
        int bh = bb * 2 + (nt >> 2);
        int d0 = (nt & 3) * 16 + quad * 4;
        u16x4_t o = pk4(aK[0] + bs.x, aK[1] + bs.y, aK[2] + bs.z, aK[3] + bs.w);
        *(u16x4_t*)(ksw + ((size_t)(bh * 128 + (m >> 4)) * 2 + (d0 >> 5)) * 512 +
                    (((d0 >> 3) & 3) * 16 + (m & 15)) * 8 + (d0 & 7)) = o;
    }
    // V (normal): -> K32-B tiles
    #pragma unroll
    for (int jj = 0; jj < 2; jj++) {
        const int nt = w * 2 + jj;
        f32x4_t aV = {};
        #pragma unroll
        for (int kc = 0; kc < 4; kc++) {
            bf16x8_t wf = *(const bf16x8_t*)(kvWs + (size_t)((8 + nt) * 4 + kc) * 512 + lane * 8);
            aV = MFMA32(xf[kc], wf, aV);
        }
        int fv = nt * 16 + col;
        int h = fv >> 6, dd = fv & 63;
        float bv = kvb[128 + fv];
        int m0 = (p0 + quad * 4) & 2047;       // base key (4 consecutive)
        int bh = bb * 2 + h;
        int kt = m0 >> 6;
        int tt = (m0 >> 5) & 1;
        int base = m0 & 31;
        int quad_b = base >> 3, j0 = base & 7;
        u16x4_t o = pk4(aV[0] + bv, aV[1] + bv, aV[2] + bv, aV[3] + bv);
        *(u16x4_t*)(vls + (((size_t)((bh * 32 + kt) * 4 + (dd >> 4)) * 2 + tt) * 512) +
                    (quad_b * 16 + (dd & 15)) * 8 + j0) = o;
    }
}

// ---------------------------------------------------------------------------
// Fused q-proj + attention + out-proj. ALL-MFMA32 K-loop:
// S^T = K·Q^T (MFMA32); exp2 -> P staged through per-wave LDS into K32
// A-operand frags (same-wave write->read, no barrier); PV and l (ones-B)
// via full-rate MFMA32. Register double-buffer of K/V kept from R10.
// Block 256 = 4 waves (qg=w&1, h=w>>1); grid (64,2,4) = 512 blocks.
__global__ __launch_bounds__(256, 2)
void k_attn_f7(const float* __restrict__ x, const unsigned short* __restrict__ qWs,
               const float* __restrict__ qb, const unsigned short* __restrict__ ksw,
               const unsigned short* __restrict__ vls, const unsigned short* __restrict__ projWs,
               const float* __restrict__ projb, float* __restrict__ out) {
    const int blkx = blockIdx.x, mod = blockIdx.y, b = blockIdx.z;
    const int t = threadIdx.x, w = t >> 6, lane = t & 63;
    const int col = lane & 15, quad = lane >> 4;
    const int qg = w & 1, h = w >> 1;
    const int bh = b * 2 + h;
    const int qbase = mod * 4096 + blkx * 64 + qg * 32;

    __shared__ unsigned short sbuf[64 * 136];   // Q frags (16KB) then O rows
    __shared__ unsigned short pls[4][2048];     // per-wave P staging (16 KB)

    // ---- q-proj: Q B-frags (scale*log2e folded), wave-local staging
    unsigned short* qarea = sbuf + w * 2048;
    const float sc = 0.125f * 1.44269504089f;
    #pragma unroll
    for (int qt = 0; qt < 2; qt++) {
        const float* xrow = x + ((size_t)b * 8192 + qbase + qt * 16 + col) * 128;
        f32x4_t acc[4] = {};
        #pragma unroll
        for (int kc = 0; kc < 4; kc++) {
            float4 xa = *(const float4*)(xrow + kc * 32 + quad * 8);
            float4 xb2 = *(const float4*)(xrow + kc * 32 + quad * 8 + 4);
            bf16x8_t xf = pk8(xa, xb2);
            #pragma unroll
            for (int j = 0; j < 4; j++) {
                bf16x8_t wf = *(const bf16x8_t*)(qWs + (size_t)((h * 4 + j) * 4 + kc) * 512 + lane * 8);
                acc[j] = MFMA32(wf, xf, acc[j]);
            }
        }
        #pragma unroll
        for (int j = 0; j < 4; j++) {
            float4 bs = *(const float4*)(qb + h * 64 + j * 16 + quad * 4);
            u16x4_t o = pk4((acc[j][0] + bs.x) * sc, (acc[j][1] + bs.y) * sc,
                            (acc[j][2] + bs.z) * sc, (acc[j][3] + bs.w) * sc);
            *(u16x4_t*)(qarea + ((size_t)(qt * 2 + (j >> 1))) * 512 +
                        (((j & 1) * 2 + (quad >> 1)) * 16 + col) * 8 + (quad & 1) * 4) = o;
        }
    }
    bf16x8_t qf[2][2];
    #pragma unroll
    for (int qt = 0; qt < 2; qt++)
        #pragma unroll
        for (int kc = 0; kc < 2; kc++)
            qf[qt][kc] = *(const bf16x8_t*)(qarea + (size_t)(qt * 2 + kc) * 512 + lane * 8);
    __syncthreads();   // Q regs loaded everywhere; sbuf free for O staging

    const unsigned short* kp0 =
        ksw + ((size_t)(bh * 128 + (1 - mod) * 64) * 2) * 512 + lane * 8;
    const unsigned short* vp0 =
        vls + ((size_t)((bh * 32 + (1 - mod) * 16) * 8)) * 512 + lane * 8;
    const bf16x8_t ones8 = { 0x3F80, 0x3F80, 0x3F80, 0x3F80,
                             0x3F80, 0x3F80, 0x3F80, 0x3F80 };
    unsigned short* parea = pls[w];

    f32x4_t O[2][4] = {};
    f32x4_t accl[2] = {};

    bf16x8_t kf0[8], kf1[8], vf0[8], vf1[8];

    auto pref0 = [&](int kt) {
        #pragma unroll
        for (int i = 0; i < 8; i++) {
            kf0[i] = *(const bf16x8_t*)(kp0 + (size_t)(kt * 8 + i) * 512);
            vf0[i] = *(const bf16x8_t*)(vp0 + (size_t)(kt * 8 + i) * 512);
        }
    };
    auto pref1 = [&](int kt) {
        #pragma unroll
        for (int i = 0; i < 8; i++) {
            kf1[i] = *(const bf16x8_t*)(kp0 + (size_t)(kt * 8 + i) * 512);
            vf1[i] = *(const bf16x8_t*)(vp0 + (size_t)(kt * 8 + i) * 512);
        }
    };
    auto body = [&](bf16x8_t (&kfc)[8], bf16x8_t (&vfc)[8]) {
        // S^T = K·Q^T
        f32x4_t ST[2][4];
        #pragma unroll
        for (int qt = 0; qt < 2; qt++)
            #pragma unroll
            for (int nb = 0; nb < 4; nb++) {
                f32x4_t sA = {};
                sA = MFMA32(kfc[nb * 2 + 0], qf[qt][0], sA);
                sA = MFMA32(kfc[nb * 2 + 1], qf[qt][1], sA);
                ST[qt][nb] = sA;
            }
        // exp2 -> P into LDS in K32 A-frag layout (same-wave, no barrier)
        #pragma unroll
        for (int qt = 0; qt < 2; qt++)
            #pragma unroll
            for (int nb = 0; nb < 4; nb++) {
                u16x4_t pk = pk4(fast_exp2(ST[qt][nb][0]), fast_exp2(ST[qt][nb][1]),
                                 fast_exp2(ST[qt][nb][2]), fast_exp2(ST[qt][nb][3]));
                *(u16x4_t*)(parea + qt * 1024 + (nb >> 1) * 512 +
                            (((nb & 1) * 2 + (quad >> 1)) * 16 + col) * 8 + (quad & 1) * 4) = pk;
            }
        // P K32 A-frags (contiguous b128 reads) -> PV + l, all MFMA32
        bf16x8_t pf[2][2];
        #pragma unroll
        for (int qt = 0; qt < 2; qt++) {
            pf[qt][0] = *(const bf16x8_t*)(parea + qt * 1024 + lane * 8);
            pf[qt][1] = *(const bf16x8_t*)(parea + qt * 1024 + 512 + lane * 8);
        }
        #pragma unroll
        for (int qt = 0; qt < 2; qt++) {
            accl[qt] = MFMA32(pf[qt][0], ones8, accl[qt]);
            accl[qt] = MFMA32(pf[qt][1], ones8, accl[qt]);
            #pragma unroll
            for (int dt = 0; dt < 4; dt++) {
                O[qt][dt] = MFMA32(pf[qt][0], vfc[dt * 2 + 0], O[qt][dt]);
                O[qt][dt] = MFMA32(pf[qt][1], vfc[dt * 2 + 1], O[qt][dt]);
            }
        }
    };

    pref0(0);
    #pragma unroll
    for (int kt2 = 0; kt2 < 8; kt2++) {
        pref1(kt2 * 2 + 1);               // loads in flight across body(kf0)
        body(kf0, vf0);
        if (kt2 < 7) pref0(kt2 * 2 + 2);  // loads in flight across body(kf1)
        body(kf1, vf1);
    }

    // ---- epilogue: O rows (query=quad*4+r, d=col) -> sbuf [64 q][136]
    #pragma unroll
    for (int qt = 0; qt < 2; qt++) {
        #pragma unroll
        for (int r = 0; r < 4; r++) {
            float rl = 1.0f / accl[qt][r];
            int qrow = qg * 32 + qt * 16 + quad * 4 + r;
            #pragma unroll
            for (int dt = 0; dt < 4; dt++)
                sbuf[qrow * 136 + h * 64 + dt * 16 + col] = f2bf(O[qt][dt][r] * rl);
        }
    }
    __syncthreads();
    // ---- out-proj: wave w -> q-tile w
    {
        const int qt2 = w;
        bf16x8_t ob[4];
        #pragma unroll
        for (int kc = 0; kc < 4; kc++)
            ob[kc] = *(const bf16x8_t*)(sbuf + (size_t)(qt2 * 16 + col) * 136 + kc * 32 + quad * 8);
        f32x4_t acc[8];
        #pragma unroll
        for (int j = 0; j < 8; j++) acc[j] = f32x4_t{};
        #pragma unroll
        for (int kc = 0; kc < 4; kc++)
            #pragma unroll
            for (int j = 0; j < 8; j++) {
                bf16x8_t wf = *(const bf16x8_t*)(projWs + (size_t)(j * 4 + kc) * 512 + lane * 8);
                acc[j] = MFMA32(wf, ob[kc], acc[j]);
            }
        const int n = b * 8192 + mod * 4096 + blkx * 64 + qt2 * 16 + col;
        #pragma unroll
        for (int j = 0; j < 8; j++) {
            int f0 = j * 16 + quad * 4;
            float4 bs = *(const float4*)(projb + f0);
            float4 o = { acc[j][0] + bs.x, acc[j][1] + bs.y,
                         acc[j][2] + bs.z, acc[j][3] + bs.w };
            *(float4*)(out + (size_t)n * 128 + f0) = o;
        }
    }
}

// ---------------------------------------------------------------------------
extern "C" void kernel_launch(void* const* d_in, const int* in_sizes, int n_in,
                              void* d_out, int out_size, void* d_ws, size_t ws_size,
                              hipStream_t stream) {
    const float* x     = (const float*)d_in[0];
    const float* qW    = (const float*)d_in[1];
    const float* qb    = (const float*)d_in[2];
    const float* kvW   = (const float*)d_in[3];
    const float* kvb   = (const float*)d_in[4];
    const float* projW = (const float*)d_in[5];
    const float* projb = (const float*)d_in[6];
    const float* srW   = (const float*)d_in[7];
    const float* srb   = (const float*)d_in[8];
    const float* lnW   = (const float*)d_in[9];
    const float* lnB   = (const float*)d_in[10];

    char* ws = (char*)d_ws;
    unsigned short* qWs    = (unsigned short*)(ws + 0);         // 32 KB
    unsigned short* kvWs   = (unsigned short*)(ws + 32768);     // 64 KB
    unsigned short* projWs = (unsigned short*)(ws + 98304);     // 32 KB
    unsigned short* srWs   = (unsigned short*)(ws + 131072);    // 128 KB
    unsigned short* ksw    = (unsigned short*)(ws + 262144);    // 2 MB
    unsigned short* vls    = (unsigned short*)(ws + 2359296);   // 2 MB

    k_prep_w<<<dim3(512), dim3(256), 0, stream>>>(qW, kvW, projW, srW,
                                                  qWs, kvWs, projWs, srWs);
    k_convkv<<<dim3(512), dim3(256), 0, stream>>>(x, srWs, srb, lnW, lnB,
                                                  kvWs, kvb, ksw, vls);
    k_attn_f7<<<dim3(64, 2, 4), dim3(256), 0, stream>>>(x, qWs, qb, ksw, vls,
                                                        projWs, projb, (float*)d_out);
}

// Round 12
// 129.179 us; speedup vs baseline: 1.1574x; 1.0243x over previous
//
#include <hip/hip_runtime.h>
#include <hip/hip_bf16.h>

#define LN_EPS 1e-5f

typedef __attribute__((ext_vector_type(8))) short bf16x8_t;
typedef __attribute__((ext_vector_type(4))) float f32x4_t;
typedef __attribute__((ext_vector_type(4))) unsigned short u16x4_t;

#define MFMA32(a, b, c) __builtin_amdgcn_mfma_f32_16x16x32_bf16(a, b, c, 0, 0, 0)

// Guaranteed-native exp2 (single v_exp_f32) — verified win in R9.
__device__ inline float fast_exp2(float x) {
#if __has_builtin(__builtin_amdgcn_exp2f)
    return __builtin_amdgcn_exp2f(x);
#else
    float r;
    asm volatile("v_exp_f32 %0, %1\n\ts_nop 0" : "=v"(r) : "v"(x));
    return r;
#endif
}

__device__ inline unsigned short f2bf(float f) {
    union { float f; unsigned int u; } v; v.f = f;
    unsigned int r = v.u + 0x7fffu + ((v.u >> 16) & 1u);
    return (unsigned short)(r >> 16);
}

__device__ inline u16x4_t pk4(float a, float b, float c, float d) {
    union { u16x4_t v; __hip_bfloat162 h[2]; } u;
    u.h[0] = __float22bfloat162_rn(float2{a, b});
    u.h[1] = __float22bfloat162_rn(float2{c, d});
    return u.v;
}
__device__ inline bf16x8_t pk8(float4 a, float4 b) {
    union { bf16x8_t v; __hip_bfloat162 h[4]; } u;
    u.h[0] = __float22bfloat162_rn(float2{a.x, a.y});
    u.h[1] = __float22bfloat162_rn(float2{a.z, a.w});
    u.h[2] = __float22bfloat162_rn(float2{b.x, b.y});
    u.h[3] = __float22bfloat162_rn(float2{b.z, b.w});
    return u.v;
}

// Fragment-layout index for [ROWS][KD] stored as MFMA fragments:
// tile (row>>4, k>>5) = 512 contiguous u16; lane=((k>>3)&3)*16+(row&15), j=k&7.
__device__ inline size_t fragidx(int row, int k, int KC) {
    return ((size_t)((row >> 4) * KC + (k >> 5))) * 512 +
           (((k >> 3) & 3) * 16 + (row & 15)) * 8 + (k & 7);
}

// ---------------------------------------------------------------------------
__global__ void k_prep_w(const float* __restrict__ qW, const float* __restrict__ kvW,
                         const float* __restrict__ projW, const float* __restrict__ srW,
                         unsigned short* __restrict__ qWs, unsigned short* __restrict__ kvWs,
                         unsigned short* __restrict__ projWs, unsigned short* __restrict__ srWs) {
    int i = blockIdx.x * 256 + threadIdx.x;
    if (i < 16384) {
        int n = i & 127, k = i >> 7;
        qWs[fragidx(n, k, 4)] = f2bf(qW[k * 128 + n]);
    } else if (i < 49152) {
        int j = i - 16384; int n = j & 255, k = j >> 8;
        kvWs[fragidx(n, k, 4)] = f2bf(kvW[k * 256 + n]);
    } else if (i < 65536) {
        int j = i - 49152; int n = j & 127, k = j >> 7;
        projWs[fragidx(n, k, 4)] = f2bf(projW[k * 128 + n]);
    } else {
        int j = i - 65536; int n = j >> 9, rem = j & 511, q = rem >> 7, c = rem & 127;
        srWs[fragidx(n, q * 128 + c, 16)] = f2bf(srW[n * 512 + c * 4 + q]);
    }
}

// ---------------------------------------------------------------------------
// Fused SR-conv + bias + LayerNorm + kv-projection (unchanged from R11).
#define XPAD 132
__global__ __launch_bounds__(256)
void k_convkv(const float* __restrict__ x, const unsigned short* __restrict__ srWs,
              const float* __restrict__ srb, const float* __restrict__ lnW,
              const float* __restrict__ lnB, const unsigned short* __restrict__ kvWs,
              const float* __restrict__ kvb, unsigned short* __restrict__ ksw,
              unsigned short* __restrict__ vls) {
    const int t = threadIdx.x, w = t >> 6, lane = t & 63;
    const int col = lane & 15, quad = lane >> 4;
    const int RT = blockIdx.x;

    __shared__ unsigned short xl[64 * XPAD];
    __shared__ unsigned short xs[4 * 512];
    __shared__ float lnred[4][16][2];

    const int pb = RT >> 7, phf = (RT >> 6) & 1;
    const int oy = (RT >> 1) & 31, ox0 = (RT & 1) * 16;
    const int n0 = phf * 4096 + 2 * oy * 64 + 2 * ox0;
    #pragma unroll
    for (int it = 0; it < 8; it++) {
        int idx = it * 256 + t;
        int chunk = idx >> 10;
        int rr = (idx >> 5) & 31;
        int c4 = idx & 31;
        float4 v = *(const float4*)(x + ((size_t)(pb * 8192 + n0 + chunk * 64 + rr)) * 128 + c4 * 4);
        *(u16x4_t*)(xl + (chunk * 32 + rr) * XPAD + c4 * 4) = pk4(v.x, v.y, v.z, v.w);
    }
    __syncthreads();

    f32x4_t acc[2] = {};
    {
        const unsigned short* wp = srWs + lane * 8;
        #pragma unroll
        for (int kc = 0; kc < 16; kc++) {
            const int q = kc >> 2, cg = kc & 3;
            const int r = (q >> 1) * 32 + 2 * col + (q & 1);
            bf16x8_t xb = *(const bf16x8_t*)(xl + r * XPAD + cg * 32 + quad * 8);
            #pragma unroll
            for (int jj = 0; jj < 2; jj++) {
                bf16x8_t wf = *(const bf16x8_t*)(wp + (size_t)((w * 2 + jj) * 16 + kc) * 512);
                acc[jj] = MFMA32(wf, xb, acc[jj]);
            }
        }
    }
    float s = 0.f, ss = 0.f;
    #pragma unroll
    for (int jj = 0; jj < 2; jj++) {
        float4 bs = *(const float4*)(srb + (w * 2 + jj) * 16 + quad * 4);
        acc[jj][0] += bs.x; acc[jj][1] += bs.y; acc[jj][2] += bs.z; acc[jj][3] += bs.w;
        #pragma unroll
        for (int r = 0; r < 4; r++) { float v = acc[jj][r]; s += v; ss += v * v; }
    }
    s += __shfl_xor(s, 16, 64);  s += __shfl_xor(s, 32, 64);
    ss += __shfl_xor(ss, 16, 64); ss += __shfl_xor(ss, 32, 64);
    if (lane < 16) { lnred[w][lane][0] = s; lnred[w][lane][1] = ss; }
    __syncthreads();
    float stot = 0.f, sstot = 0.f;
    #pragma unroll
    for (int ww = 0; ww < 4; ww++) { stot += lnred[ww][col][0]; sstot += lnred[ww][col][1]; }
    float mean = stot * (1.0f / 128.0f);
    float var = sstot * (1.0f / 128.0f) - mean * mean;
    float rs = rsqrtf(var + LN_EPS);
    #pragma unroll
    for (int jj = 0; jj < 2; jj++) {
        int f0 = (w * 2 + jj) * 16 + quad * 4;
        float4 g = *(const float4*)(lnW + f0);
        float4 be = *(const float4*)(lnB + f0);
        u16x4_t o = pk4((acc[jj][0] - mean) * rs * g.x + be.x,
                        (acc[jj][1] - mean) * rs * g.y + be.y,
                        (acc[jj][2] - mean) * rs * g.z + be.z,
                        (acc[jj][3] - mean) * rs * g.w + be.w);
        *(u16x4_t*)(xs + ((size_t)(f0 >> 5)) * 512 +
                    (((f0 >> 3) & 3) * 16 + col) * 8 + (f0 & 7)) = o;
    }
    __syncthreads();
    bf16x8_t xf[4];
    #pragma unroll
    for (int kc = 0; kc < 4; kc++)
        xf[kc] = *(const bf16x8_t*)(xs + (size_t)kc * 512 + lane * 8);
    const int p0 = RT * 16;
    const int bb = p0 >> 11;
    #pragma unroll
    for (int jj = 0; jj < 2; jj++) {
        const int nt = w * 2 + jj;
        f32x4_t aK = {};
        #pragma unroll
        for (int kc = 0; kc < 4; kc++) {
            bf16x8_t wf = *(const bf16x8_t*)(kvWs + (size_t)(nt * 4 + kc) * 512 + lane * 8);
            aK = MFMA32(wf, xf[kc], aK);
        }
        float4 bs = *(const float4*)(kvb + nt * 16 + quad * 4);
        int m = (p0 + col) & 2047;
        int bh = bb * 2 + (nt >> 2);
        int d0 = (nt & 3) * 16 + quad * 4;
        u16x4_t o = pk4(aK[0] + bs.x, aK[1] + bs.y, aK[2] + bs.z, aK[3] + bs.w);
        *(u16x4_t*)(ksw + ((size_t)(bh * 128 + (m >> 4)) * 2 + (d0 >> 5)) * 512 +
                    (((d0 >> 3) & 3) * 16 + (m & 15)) * 8 + (d0 & 7)) = o;
    }
    #pragma unroll
    for (int jj = 0; jj < 2; jj++) {
        const int nt = w * 2 + jj;
        f32x4_t aV = {};
        #pragma unroll
        for (int kc = 0; kc < 4; kc++) {
            bf16x8_t wf = *(const bf16x8_t*)(kvWs + (size_t)((8 + nt) * 4 + kc) * 512 + lane * 8);
            aV = MFMA32(xf[kc], wf, aV);
        }
        int fv = nt * 16 + col;
        int h = fv >> 6, dd = fv & 63;
        float bv = kvb[128 + fv];
        int m0 = (p0 + quad * 4) & 2047;
        int bh = bb * 2 + h;
        int kt = m0 >> 6;
        int tt = (m0 >> 5) & 1;
        int base = m0 & 31;
        int quad_b = base >> 3, j0 = base & 7;
        u16x4_t o = pk4(aV[0] + bv, aV[1] + bv, aV[2] + bv, aV[3] + bv);
        *(u16x4_t*)(vls + (((size_t)((bh * 32 + kt) * 4 + (dd >> 4)) * 2 + tt) * 512) +
                    (quad_b * 16 + (dd & 15)) * 8 + j0) = o;
    }
}

// ---------------------------------------------------------------------------
// Fused q-proj + attention + out-proj.  64 QUERIES/WAVE + KEY-SPLIT:
// wave (ks=w&1, h=w>>1) handles 64 queries x 512 keys (half) -> per-wave K/V
// traffic halves (1 MB/CU) at unchanged wave count (2/SIMD).  Softmax has no
// max-tracking so the split combine is a pure fp32 ADD (per-head sequential
// LDS combine).  All-MFMA32 body, native exp2, register P via per-wave LDS.
// Block 256 = 4 waves; grid (64, 2, 4) = 512 blocks.
__global__ __launch_bounds__(256, 2)
void k_attn_f8(const float* __restrict__ x, const unsigned short* __restrict__ qWs,
               const float* __restrict__ qb, const unsigned short* __restrict__ ksw,
               const unsigned short* __restrict__ vls, const unsigned short* __restrict__ projWs,
               const float* __restrict__ projb, float* __restrict__ out) {
    const int blkx = blockIdx.x, mod = blockIdx.y, b = blockIdx.z;
    const int t = threadIdx.x, w = t >> 6, lane = t & 63;
    const int col = lane & 15, quad = lane >> 4;
    const int ks = w & 1, h = w >> 1;
    const int bh = b * 2 + h;
    const int qbase = mod * 4096 + blkx * 64;      // 64 queries per block

    __shared__ unsigned short sbuf[64 * 136];      // Q frags (16KB) then O rows
    __shared__ unsigned short pls[4][4096];        // per-wave P staging (32 KB)
    __shared__ float Ocomb[64 * 68];               // key-split combine (17 KB)
    __shared__ float lcomb[64];

    // ---- q-proj: wave (ks,h) computes q-tiles {2ks, 2ks+1} of head h
    const float sc = 0.125f * 1.44269504089f;
    #pragma unroll
    for (int qtl = 0; qtl < 2; qtl++) {
        const int qt = ks * 2 + qtl;
        const float* xrow = x + ((size_t)b * 8192 + qbase + qt * 16 + col) * 128;
        f32x4_t acc[4] = {};
        #pragma unroll
        for (int kc = 0; kc < 4; kc++) {
            float4 xa = *(const float4*)(xrow + kc * 32 + quad * 8);
            float4 xb2 = *(const float4*)(xrow + kc * 32 + quad * 8 + 4);
            bf16x8_t xf = pk8(xa, xb2);
            #pragma unroll
            for (int j = 0; j < 4; j++) {
                bf16x8_t wf = *(const bf16x8_t*)(qWs + (size_t)((h * 4 + j) * 4 + kc) * 512 + lane * 8);
                acc[j] = MFMA32(wf, xf, acc[j]);
            }
        }
        #pragma unroll
        for (int j = 0; j < 4; j++) {
            float4 bs = *(const float4*)(qb + h * 64 + j * 16 + quad * 4);
            u16x4_t o = pk4((acc[j][0] + bs.x) * sc, (acc[j][1] + bs.y) * sc,
                            (acc[j][2] + bs.z) * sc, (acc[j][3] + bs.w) * sc);
            *(u16x4_t*)(sbuf + (size_t)h * 4096 + ((size_t)(qt * 2 + (j >> 1))) * 512 +
                        (((j & 1) * 2 + (quad >> 1)) * 16 + col) * 8 + (quad & 1) * 4) = o;
        }
    }
    __syncthreads();
    bf16x8_t qf[4][2];
    #pragma unroll
    for (int qt = 0; qt < 4; qt++)
        #pragma unroll
        for (int kc = 0; kc < 2; kc++)
            qf[qt][kc] = *(const bf16x8_t*)(sbuf + (size_t)h * 4096 +
                                            (size_t)(qt * 2 + kc) * 512 + lane * 8);
    __syncthreads();   // Q loaded into regs everywhere; sbuf free for O rows

    const unsigned short* kp0 =
        ksw + ((size_t)(bh * 128 + (1 - mod) * 64) * 2) * 512 + lane * 8;
    const unsigned short* vp0 =
        vls + ((size_t)((bh * 32 + (1 - mod) * 16) * 8)) * 512 + lane * 8;
    const bf16x8_t ones8 = { 0x3F80, 0x3F80, 0x3F80, 0x3F80,
                             0x3F80, 0x3F80, 0x3F80, 0x3F80 };
    unsigned short* parea = pls[w];

    f32x4_t O[4][4] = {};
    f32x4_t accl[4] = {};

    for (int kti = 0; kti < 8; kti++) {
        const int kt = ks * 8 + kti;
        bf16x8_t kf[8], vf[8];
        #pragma unroll
        for (int i = 0; i < 8; i++) {
            kf[i] = *(const bf16x8_t*)(kp0 + (size_t)(kt * 8 + i) * 512);
            vf[i] = *(const bf16x8_t*)(vp0 + (size_t)(kt * 8 + i) * 512);
        }
        // process q-tiles in pairs to bound live registers
        #pragma unroll
        for (int qp = 0; qp < 2; qp++) {
            f32x4_t ST[2][4];
            #pragma unroll
            for (int qtl = 0; qtl < 2; qtl++) {
                const int qt = qp * 2 + qtl;
                #pragma unroll
                for (int nb = 0; nb < 4; nb++) {
                    f32x4_t sA = {};
                    sA = MFMA32(kf[nb * 2 + 0], qf[qt][0], sA);
                    sA = MFMA32(kf[nb * 2 + 1], qf[qt][1], sA);
                    ST[qtl][nb] = sA;
                }
            }
            // exp2 -> P into LDS K32 A-frag layout (same-wave, no barrier)
            #pragma unroll
            for (int qtl = 0; qtl < 2; qtl++)
                #pragma unroll
                for (int nb = 0; nb < 4; nb++) {
                    u16x4_t pk = pk4(fast_exp2(ST[qtl][nb][0]), fast_exp2(ST[qtl][nb][1]),
                                     fast_exp2(ST[qtl][nb][2]), fast_exp2(ST[qtl][nb][3]));
                    *(u16x4_t*)(parea + (qp * 2 + qtl) * 1024 + (nb >> 1) * 512 +
                                (((nb & 1) * 2 + (quad >> 1)) * 16 + col) * 8 + (quad & 1) * 4) = pk;
                }
            // P K32 A-frags -> l + PV (all MFMA32)
            #pragma unroll
            for (int qtl = 0; qtl < 2; qtl++) {
                const int qt = qp * 2 + qtl;
                bf16x8_t pf0 = *(const bf16x8_t*)(parea + qt * 1024 + lane * 8);
                bf16x8_t pf1 = *(const bf16x8_t*)(parea + qt * 1024 + 512 + lane * 8);
                accl[qt] = MFMA32(pf0, ones8, accl[qt]);
                accl[qt] = MFMA32(pf1, ones8, accl[qt]);
                #pragma unroll
                for (int dt = 0; dt < 4; dt++) {
                    O[qt][dt] = MFMA32(pf0, vf[dt * 2 + 0], O[qt][dt]);
                    O[qt][dt] = MFMA32(pf1, vf[dt * 2 + 1], O[qt][dt]);
                }
            }
        }
    }

    // ---- key-split combine (pure add; per-head sequential fp32 LDS)
    #pragma unroll
    for (int hp = 0; hp < 2; hp++) {
        if (h == hp && ks == 1) {
            #pragma unroll
            for (int qt = 0; qt < 4; qt++)
                #pragma unroll
                for (int r = 0; r < 4; r++) {
                    int qrow = qt * 16 + quad * 4 + r;
                    #pragma unroll
                    for (int dt = 0; dt < 4; dt++)
                        Ocomb[qrow * 68 + dt * 16 + col] = O[qt][dt][r];
                    if (col == 0) lcomb[qrow] = accl[qt][r];
                }
        }
        __syncthreads();
        if (h == hp && ks == 0) {
            #pragma unroll
            for (int qt = 0; qt < 4; qt++)
                #pragma unroll
                for (int r = 0; r < 4; r++) {
                    int qrow = qt * 16 + quad * 4 + r;
                    float lt = accl[qt][r] + lcomb[qrow];
                    float rl = 1.0f / lt;
                    #pragma unroll
                    for (int dt = 0; dt < 4; dt++) {
                        float ov = O[qt][dt][r] + Ocomb[qrow * 68 + dt * 16 + col];
                        sbuf[qrow * 136 + hp * 64 + dt * 16 + col] = f2bf(ov * rl);
                    }
                }
        }
        __syncthreads();
    }

    // ---- out-proj: wave w -> q-tile w (16 queries, all 128 features)
    {
        const int qt2 = w;
        bf16x8_t ob[4];
        #pragma unroll
        for (int kc = 0; kc < 4; kc++)
            ob[kc] = *(const bf16x8_t*)(sbuf + (size_t)(qt2 * 16 + col) * 136 + kc * 32 + quad * 8);
        f32x4_t acc[8];
        #pragma unroll
        for (int j = 0; j < 8; j++) acc[j] = f32x4_t{};
        #pragma unroll
        for (int kc = 0; kc < 4; kc++)
            #pragma unroll
            for (int j = 0; j < 8; j++) {
                bf16x8_t wf = *(const bf16x8_t*)(projWs + (size_t)(j * 4 + kc) * 512 + lane * 8);
                acc[j] = MFMA32(wf, ob[kc], acc[j]);
            }
        const int n = b * 8192 + qbase + qt2 * 16 + col;
        #pragma unroll
        for (int j = 0; j < 8; j++) {
            int f0 = j * 16 + quad * 4;
            float4 bs = *(const float4*)(projb + f0);
            float4 o = { acc[j][0] + bs.x, acc[j][1] + bs.y,
                         acc[j][2] + bs.z, acc[j][3] + bs.w };
            *(float4*)(out + (size_t)n * 128 + f0) = o;
        }
    }
}

// ---------------------------------------------------------------------------
extern "C" void kernel_launch(void* const* d_in, const int* in_sizes, int n_in,
                              void* d_out, int out_size, void* d_ws, size_t ws_size,
                              hipStream_t stream) {
    const float* x     = (const float*)d_in[0];
    const float* qW    = (const float*)d_in[1];
    const float* qb    = (const float*)d_in[2];
    const float* kvW   = (const float*)d_in[3];
    const float* kvb   = (const float*)d_in[4];
    const float* projW = (const float*)d_in[5];
    const float* projb = (const float*)d_in[6];
    const float* srW   = (const float*)d_in[7];
    const float* srb   = (const float*)d_in[8];
    const float* lnW   = (const float*)d_in[9];
    const float* lnB   = (const float*)d_in[10];

    char* ws = (char*)d_ws;
    unsigned short* qWs    = (unsigned short*)(ws + 0);         // 32 KB
    unsigned short* kvWs   = (unsigned short*)(ws + 32768);     // 64 KB
    unsigned short* projWs = (unsigned short*)(ws + 98304);     // 32 KB
    unsigned short* srWs   = (unsigned short*)(ws + 131072);    // 128 KB
    unsigned short* ksw    = (unsigned short*)(ws + 262144);    // 2 MB
    unsigned short* vls    = (unsigned short*)(ws + 2359296);   // 2 MB

    k_prep_w<<<dim3(512), dim3(256), 0, stream>>>(qW, kvW, projW, srW,
                                                  qWs, kvWs, projWs, srWs);
    k_convkv<<<dim3(512), dim3(256), 0, stream>>>(x, srWs, srb, lnW, lnB,
                                                  kvWs, kvb, ksw, vls);
    k_attn_f8<<<dim3(64, 2, 4), dim3(256), 0, stream>>>(x, qWs, qb, ksw, vls,
                                                        projWs, projb, (float*)d_out);
}